// Round 14
// baseline (239.627 us; speedup 1.0000x reference)
//
#include <hip/hip_runtime.h>
#include <hip/hip_fp16.h>
#include <cstdint>

// Problem constants
#define T3   1536   // (NGRAM+1)*TM
#define TMQ  512    // TM
#define BB   4      // batch
#define EE   1024   // embed
#define HH   16     // heads
#define HD   64     // head dim
#define NBK  32     // buckets
#define BHH  64     // B*H

#define LOG2E 1.44269504f
#define SM_SHIFT 4.0f   // fixed softmax shift: p = exp(s - 4); safe since s <~ 12

typedef _Float16 half8 __attribute__((ext_vector_type(8)));
typedef float    f32x4 __attribute__((ext_vector_type(4)));

// XOR swizzle for [*][64] fp16 tiles (128B rows) - attn kernel + gemm BK=64 (T2/G4).
#define SWZ(r, o) ((o) ^ (((r) & 7) << 4))

__device__ inline void gl_lds16(const void* g, void* l) {
    __builtin_amdgcn_global_load_lds(
        (const __attribute__((address_space(1))) uint32_t*)g,
        (__attribute__((address_space(3))) uint32_t*)l, 16, 0, 0);
}

#define VM_WAIT0() asm volatile("s_waitcnt vmcnt(0)" ::: "memory")
#define BARRIER()  __builtin_amdgcn_s_barrier()

// ---------------------------------------------------------------------------
// Fused fp32 -> fp16 conversion for all six tensors in ONE launch.
// dst layout contiguous: hs_h | Wq | Wk | Wv | Wo | Wr.
// ---------------------------------------------------------------------------
__global__ __launch_bounds__(256) void cvt_all(
    const float* __restrict__ hs, const float* __restrict__ Wq,
    const float* __restrict__ Wk, const float* __restrict__ Wv,
    const float* __restrict__ Wo, const float* __restrict__ Wr,
    __half* __restrict__ dst)
{
    const long i = (long)blockIdx.x * 256 + threadIdx.x;   // vec4 index
    const float* src; long off;
    if (i < 1572864L) { src = hs; off = i; }
    else {
        const long j = i - 1572864L;
        const int  w = (int)(j >> 18);
        const long r = j & 262143L;
        src = (w == 0) ? Wq : (w == 1) ? Wk : (w == 2) ? Wv : (w == 3) ? Wo : Wr;
        off = r;
    }
    const float4 v = ((const float4*)src)[off];
    const __half2 h0 = __floats2half2_rn(v.x, v.y);
    const __half2 h1 = __floats2half2_rn(v.z, v.w);
    uint2 u;
    u.x = *(const unsigned int*)&h0;
    u.y = *(const unsigned int*)&h1;
    ((uint2*)dst)[i] = u;
}

// ---------------------------------------------------------------------------
// fp16 MFMA GEMM (NT): C = (A @ W^T + bias) * scale + offs, K = 1024.
// r14: BM=BN=256, BK=64 (128B rows), 512 thr (8 waves 2Mx4N), wave tile
// 128x64 (acc 8x4), 16x16x32 MFMA. r13 post-mortem: 6 rounds pinned at
// MfmaUtil 17-19% because the 128^2/4-wave geometry is DS-pipe-bound
// (~2300cy DS vs ~320cy MFMA per phase: read-bytes/FLOP too high). 256^2
// drops read/FLOP 25%, halves staging+barriers per FLOP; catalog-verified
// 655-682 TF at 2-phase K=1024 (m230/m248) vs our 475.
// Same r12 discipline: static buffer pairs referenced literally, ONE
// vmcnt(0)+s_barrier per K-step AFTER compute, setprio on MFMA clusters,
// r8 conflict-free swizzle (measured 0 conflicts). LDS 128 KB -> 1 blk/CU.
// No min-waves hint (r5/r6: hints spill).
// MODE 0: fused QKV+Wr, grid (14,24): bx 0..11 -> q/k/v (4 each), 12..13 Wr.
// MODE 2: Wo -> fp32 row-major (M,1024), grid (4,24).
// ---------------------------------------------------------------------------
template<int MODE>
__global__ __launch_bounds__(512) void gemm16(
    const __half* __restrict__ A,
    const __half* __restrict__ Wa, const __half* __restrict__ Wb,
    const __half* __restrict__ Wc, const __half* __restrict__ Wd,
    const float* __restrict__ ba, const float* __restrict__ bb,
    const float* __restrict__ bc, const float* __restrict__ bd,
    void* __restrict__ oa, void* __restrict__ ob,
    void* __restrict__ oc, void* __restrict__ od)
{
    // four DISTINCT static LDS objects (alias analysis can separate them)
    __shared__ __half As0[256 * 64];   // 32 KB each
    __shared__ __half Bs0[256 * 64];
    __shared__ __half As1[256 * 64];
    __shared__ __half Bs1[256 * 64];   // total 128 KB -> 1 block/CU

    const int tid  = threadIdx.x;
    const int w    = tid >> 6, lane = tid & 63;      // w 0..7

    // bijective XCD swizzle (grid.x*grid.y multiple of 8)
    const int GX   = (MODE == 0) ? 14 : 4;
    const int bidl = blockIdx.x + GX * blockIdx.y;
    const int xcd  = bidl & 7, idx = bidl >> 3;
    const int bx   = idx % GX;
    const int by   = (idx / GX) * 8 + xcd;           // 0..23
    const int m0   = by * 256;

    const __half* Wsel; const float* bsel; void* osel;
    float scale, offs; int n0; int sel = 0;
    if (MODE == 0) {
        sel  = (bx < 12) ? (bx >> 2) : 3;
        n0   = (bx < 12) ? (bx & 3) * 256 : (bx - 12) * 256;
        Wsel = sel == 0 ? Wa : (sel == 1 ? Wb : (sel == 2 ? Wc : Wd));
        bsel = sel == 0 ? ba : (sel == 1 ? bb : (sel == 2 ? bc : bd));
        osel = sel == 0 ? oa : (sel == 1 ? ob : (sel == 2 ? oc : od));
        scale = (sel == 0) ? 0.125f * LOG2E : (sel == 3 ? LOG2E : 1.0f);
        offs  = (sel == 3) ? -SM_SHIFT * LOG2E : 0.0f;
    } else {
        n0 = bx * 256; Wsel = Wa; bsel = ba; osel = oa;
        scale = 1.0f; offs = 0.0f;
    }

    f32x4 acc[8][4];
    #pragma unroll
    for (int i = 0; i < 8; ++i)
        #pragma unroll
        for (int j = 0; j < 4; ++j) acc[i][j] = (f32x4){0.f, 0.f, 0.f, 0.f};

    const int wr = w >> 2, wc = w & 3;               // 2M x 4N wave grid
    const int lrow = lane & 15, lkg = lane >> 4;
    // fragment base byte offsets (row*128B); per-m/n advance = 16 rows = 2048 B
    const int aoff = (wr * 128 + lrow) * 128;        // wave owns 128 A-rows
    const int boff = (wc * 64 + lrow) * 128;         // and 64 B-rows
    const int rswz = (lrow & 7) << 4;                // read-side XOR

    // staging: 512 thr x 4 calls x 16B = 32 KB per tensor per K-step.
    // wave w owns tile rows [w*32, w*32+32); source col pre-swizzled
    // (slot ^ row&7) - rule #21 both-sides (r8 geometry, 0 conflicts).
    const int tilebase = w * 4096;
    const char* Ab  = (const char*)A;
    const char* Wb8 = (const char*)Wsel;
    int srow[4], scol[4];
    #pragma unroll
    for (int i = 0; i < 4; ++i) {
        const int off = tilebase + i * 1024 + lane * 16;
        srow[i] = off >> 7;                                 // tile row 0..255
        scol[i] = (((off >> 4) & 7) ^ (srow[i] & 7)) * 16;  // swizzled src col
    }

#define STAGEK(AS, BS, K0) do {                                                   \
    _Pragma("unroll")                                                             \
    for (int i = 0; i < 4; ++i) {                                                 \
        gl_lds16(Ab  + (size_t)(m0 + srow[i]) * 2048 + (size_t)(K0) * 2 + scol[i],\
                 (char*)(AS) + tilebase + i * 1024);                              \
        gl_lds16(Wb8 + (size_t)(n0 + srow[i]) * 2048 + (size_t)(K0) * 2 + scol[i],\
                 (char*)(BS) + tilebase + i * 1024);                              \
    }                                                                             \
} while (0)

#define COMPUTEK(AS, BS) do {                                                     \
    _Pragma("unroll")                                                             \
    for (int ks = 0; ks < 2; ++ks) {                                              \
        const int kb = (ks * 64 + lkg * 16) ^ rswz;                               \
        half8 af[8], bf[4];                                                       \
        _Pragma("unroll")                                                         \
        for (int m = 0; m < 8; ++m)                                               \
            af[m] = *(const half8*)((const char*)(AS) + aoff + m * 2048 + kb);    \
        _Pragma("unroll")                                                         \
        for (int n = 0; n < 4; ++n)                                               \
            bf[n] = *(const half8*)((const char*)(BS) + boff + n * 2048 + kb);    \
        __builtin_amdgcn_s_setprio(1);                                            \
        _Pragma("unroll")                                                         \
        for (int m = 0; m < 8; ++m)                                               \
            _Pragma("unroll")                                                     \
            for (int n = 0; n < 4; ++n)                                           \
                acc[m][n] = __builtin_amdgcn_mfma_f32_16x16x32_f16(af[m], bf[n],  \
                                                                   acc[m][n], 0, 0, 0);\
        __builtin_amdgcn_s_setprio(0);                                            \
    }                                                                             \
} while (0)

    // prologue: stage K-step 0 into buf0, drain, barrier
    STAGEK(As0, Bs0, 0);
    VM_WAIT0();
    BARRIER();

    // 16 K-steps of BK=64 as 8 double-phases; ONE vmcnt(0)+barrier per step,
    // placed AFTER compute so the staged loads fly during the compute phase.
    #pragma unroll 1
    for (int t = 0; t < 8; ++t) {
        const int kA = t * 128;
        // phase A: stage next step into buf1, compute buf0
        STAGEK(As1, Bs1, kA + 64);
        COMPUTEK(As0, Bs0);
        VM_WAIT0();                 // buf1 staged (flew during compute)
        BARRIER();                  // + all waves done reading buf0
        // phase B: stage next step into buf0, compute buf1
        if (t < 7) STAGEK(As0, Bs0, kA + 128);
        COMPUTEK(As1, Bs1);
        VM_WAIT0();
        BARRIER();
    }

#undef STAGEK
#undef COMPUTEK

    // epilogue: C/D layout col = lane&15, row = (lane>>4)*4 + reg
    const int col_l  = lane & 15;
    const int row_l4 = (lane >> 4) * 4;
    #pragma unroll
    for (int n = 0; n < 4; ++n) {
        const int gcol = n0 + wc * 64 + n * 16 + col_l;
        const float bias = bsel[gcol];
        #pragma unroll
        for (int m = 0; m < 8; ++m) {
            #pragma unroll
            for (int j = 0; j < 4; ++j) {
                const int grow = m0 + wr * 128 + m * 16 + row_l4 + j;
                const float cval = (acc[m][n][j] + bias) * scale + offs;
                if (MODE == 0) {
                    const int t3 = grow >> 2, bb2 = grow & 3;
                    if (sel == 3) {   // vals (stream, BH, TM, NB), fp32
                        const int st = t3 >> 9, tm = t3 & 511;
                        const int nb = gcol >> 4, hh2 = gcol & 15;
                        ((float*)osel)[(((size_t)(st * BHH + bb2 * HH + hh2)) * TMQ + tm) * NBK + nb] = cval;
                    } else {
                        const int hh2 = gcol >> 6, d = gcol & 63;
                        __half* oh = (__half*)osel;
                        const __half hv = __float2half(cval);
                        if (sel == 2)  // V transposed: (BH, hd, T3)
                            oh[((size_t)((bb2 * HH + hh2) * HD + d)) * T3 + t3] = hv;
                        else           // Q, K: (BH, T3, hd)
                            oh[(((size_t)(bb2 * HH + hh2)) * T3 + t3) * HD + d] = hv;
                    }
                } else {
                    ((float*)osel)[(size_t)grow * EE + gcol] = cval;
                }
            }
        }
    }
}

// ---------------------------------------------------------------------------
// MFMA fused attention, QBLK=128: block = (s, bh, 128 q-rows), 8 waves x 16
// q-rows. Fixed-shift softmax (p = exp2(qk' + vals'[idx] + mask*log2e)),
// per-lane l, reduced once at the end. Register-prefetch of K/Vt + idx/mask
// (T14), setprio (T5). LDS 48 KB. Balanced XCD map: 768 blocks, per XCD
// 64 ngram + 32 main, ngram first.
// NOTE (r5/r6): NEVER add a min-waves hint (spills the prefetch state).
// ---------------------------------------------------------------------------
__global__ __launch_bounds__(512) void attn_mfma(
    const __half* __restrict__ q, const __half* __restrict__ k,
    const __half* __restrict__ vt, const float* __restrict__ vals,
    const float* __restrict__ self_mask, const float* __restrict__ ngram_mask,
    const int* __restrict__ ibm, const int* __restrict__ ibr,
    __half* __restrict__ attn_pre)
{
    __shared__ __half QP [128 * 64];   // 16 KB: Q staging -> reused as P
    __shared__ __half Ks [64 * 64];    //  8 KB [key][d] swizzled
    __shared__ __half Vts[64 * 64];    //  8 KB [d][key] swizzled
    __shared__ float  vals_s[128 * NBK];   // 16 KB

    // balanced XCD mapping: xcd = bid&7; rr<64 -> ngram, rr>=64 -> main
    const int bid = blockIdx.x;
    const int xcd = bid & 7, rr = bid >> 3;          // rr in [0,96)
    int s, bh, qt;
    if (rr < 64) { const int g = xcd * 64 + rr; s = 1 + (g >> 8); bh = (g >> 2) & 63; qt = g & 3; }
    else         { const int mi = xcd * 32 + (rr - 64); s = 0; bh = mi >> 2; qt = mi & 3; }
    const int b = bh >> 4, h = bh & 15;
    const int tid = threadIdx.x;                     // 0..511
    const int w = tid >> 6, lane = tid & 63;         // w 0..7
    const int lc = lane & 15, lg = lane >> 4;
    const int nch = (s == 0) ? 8 : 16;

    // ---- stage Q (swizzled, into QP) + vals (linear): 16 KB each ----
    {
        const char* qg = (const char*)(q + ((size_t)bh * T3 + s * TMQ + qt * 128) * HD);
        const char* vg = (const char*)(vals + (((size_t)s * BHH + bh) * TMQ + qt * 128) * NBK);
        #pragma unroll
        for (int p = 0; p < 2; ++p) {
            const int u = tid + p * 512;             // 0..1023
            const int row = u >> 3, sub = (u & 7) * 16;
            *(uint4*)((char*)QP + row * 128 + SWZ(row, sub)) = *(const uint4*)(qg + (size_t)u * 16);
            *(uint4*)((char*)vals_s + (size_t)u * 16)        = *(const uint4*)(vg + (size_t)u * 16);
        }
    }

    // ---- prologue prefetch: chunk 0 K/Vt + idx/mask into registers ----
    uint4 ku0, vu0;
    int   ix[4][4];
    float mk[4][4];
    {
        const char* kg = (const char*)(k + (size_t)bh * T3 * HD);          // t3b(0)=0
        const char* vg = (const char*)(vt + (size_t)bh * HD * T3);
        ku0 = *(const uint4*)(kg + (size_t)tid * 16);
        vu0 = *(const uint4*)(vg + (size_t)(tid >> 3) * (T3 * 2) + (tid & 7) * 16);
        #pragma unroll
        for (int j = 0; j < 4; ++j) {
            const int t = qt * 128 + w * 16 + lg * 4 + j;
            const int* ip; const float* mp;
            if (s == 0) { ip = ibm + ((size_t)b * TMQ + t) * TMQ + lc;
                          mp = self_mask + (size_t)t * TMQ + lc; }
            else        { ip = ibr + ((size_t)b * TMQ + t) * (2 * TMQ) + lc;
                          mp = ngram_mask + ((size_t)(s - 1) * TMQ + t) * (2 * TMQ) + lc; }
            #pragma unroll
            for (int n = 0; n < 4; ++n) { ix[j][n] = ip[n * 16]; mk[j][n] = mp[n * 16]; }
        }
    }
    __syncthreads();   // QP(Q)/vals_s staged

    // hoisted Q A-fragments (row = local q = w*16 + lc, in [0,128))
    half8 aq[2];
    {
        const int qr = w * 16 + lc;
        const char* qb = (const char*)QP + qr * 128;
        aq[0] = *(const half8*)(qb + SWZ(qr, lg * 16));
        aq[1] = *(const half8*)(qb + SWZ(qr, 64 + lg * 16));
    }

    f32x4 o[4];
    #pragma unroll
    for (int nd = 0; nd < 4; ++nd) o[nd] = (f32x4){0.f, 0.f, 0.f, 0.f};
    float l_p[4] = {0.f, 0.f, 0.f, 0.f};

    for (int c = 0; c < nch; ++c) {
        // ---- ds_write prefetched K/Vt (one uint4 per tensor per thread) ----
        if (c > 0) __syncthreads();   // all waves done reading Ks/Vts of c-1
        {
            const int r0 = tid >> 3, s0 = (tid & 7) * 16;   // r0 0..63
            *(uint4*)((char*)Ks  + r0 * 128 + SWZ(r0, s0)) = ku0;
            *(uint4*)((char*)Vts + r0 * 128 + SWZ(r0, s0)) = vu0;
        }
        __syncthreads();              // staged (also fences aq reads, c==0)

        // ---- issue next chunk's K/Vt loads (hide under QK+exp+PV) ----
        if (c + 1 < nch) {
            const int jn  = (c + 1) * 64;
            const int t3n = (jn < TMQ) ? jn : s * TMQ + (jn - TMQ);
            const char* kg = (const char*)(k + ((size_t)bh * T3 + t3n) * HD);
            const char* vg = (const char*)(vt + (size_t)bh * HD * T3 + t3n);
            ku0 = *(const uint4*)(kg + (size_t)tid * 16);
            vu0 = *(const uint4*)(vg + (size_t)(tid >> 3) * (T3 * 2) + (tid & 7) * 16);
        }

        // ---- QK^T: D[q_local][key] (q pre-scaled by 0.125*log2e) ----
        f32x4 sc[4];
        #pragma unroll
        for (int n = 0; n < 4; ++n) sc[n] = (f32x4){0.f, 0.f, 0.f, 0.f};
        __builtin_amdgcn_s_setprio(1);
        #pragma unroll
        for (int ks = 0; ks < 2; ++ks) {
            #pragma unroll
            for (int n = 0; n < 4; ++n) {
                const int kr = n * 16 + lc;
                const half8 bk = *(const half8*)((const char*)Ks + kr * 128 + SWZ(kr, ks * 64 + lg * 16));
                sc[n] = __builtin_amdgcn_mfma_f32_16x16x32_f16(aq[ks], bk, sc[n], 0, 0, 0);
            }
        }
        __builtin_amdgcn_s_setprio(0);

        // ---- gather + exp2 + P write + per-lane partial sum ----
        // element: row q_local = w*16 + lg*4 + j, col key = n*16 + lc
        #pragma unroll
        for (int j = 0; j < 4; ++j) {
            const int ql = w * 16 + lg * 4 + j;
            const float* vr = vals_s + ql * NBK;
            float p[4];
            #pragma unroll
            for (int n = 0; n < 4; ++n) {
                const float sv = fmaf(mk[j][n], LOG2E, sc[n][j] + vr[ix[j][n]]);
                p[n] = __builtin_amdgcn_exp2f(sv);
            }
            l_p[j] += (p[0] + p[1]) + (p[2] + p[3]);
            char* pb = (char*)QP + ql * 128;
            *(__half*)(pb + SWZ(ql, (0 * 16 + lc) * 2)) = __float2half(p[0]);
            *(__half*)(pb + SWZ(ql, (1 * 16 + lc) * 2)) = __float2half(p[1]);
            *(__half*)(pb + SWZ(ql, (2 * 16 + lc) * 2)) = __float2half(p[2]);
            *(__half*)(pb + SWZ(ql, (3 * 16 + lc) * 2)) = __float2half(p[3]);
        }

        // ---- issue next chunk's idx/mask loads ----
        if (c + 1 < nch) {
            const int jn = (c + 1) * 64;
            #pragma unroll
            for (int j = 0; j < 4; ++j) {
                const int t = qt * 128 + w * 16 + lg * 4 + j;
                const int* ip; const float* mp;
                if (s == 0) { ip = ibm + ((size_t)b * TMQ + t) * TMQ + jn + lc;
                              mp = self_mask + (size_t)t * TMQ + jn + lc; }
                else        { ip = ibr + ((size_t)b * TMQ + t) * (2 * TMQ) + jn + lc;
                              mp = ngram_mask + ((size_t)(s - 1) * TMQ + t) * (2 * TMQ) + jn + lc; }
                #pragma unroll
                for (int n = 0; n < 4; ++n) { ix[j][n] = ip[n * 16]; mk[j][n] = mp[n * 16]; }
            }
        }
        __threadfence_block();   // P-writes visible (QP rows are per-wave)

        // ---- PV: O[q_local][d] += P[q][key] * Vt[d][key] ----
        __builtin_amdgcn_s_setprio(1);
        #pragma unroll
        for (int ks = 0; ks < 2; ++ks) {
            const int ar = w * 16 + lc;
            const half8 ap = *(const half8*)((const char*)QP + ar * 128 + SWZ(ar, ks * 64 + lg * 16));
            #pragma unroll
            for (int nd = 0; nd < 4; ++nd) {
                const int vr2 = nd * 16 + lc;
                const half8 bv = *(const half8*)((const char*)Vts + vr2 * 128 + SWZ(vr2, ks * 64 + lg * 16));
                o[nd] = __builtin_amdgcn_mfma_f32_16x16x32_f16(ap, bv, o[nd], 0, 0, 0);
            }
        }
        __builtin_amdgcn_s_setprio(0);
    }

    // ---- final cross-lane sum reduce (once) + normalize + write fp16 ----
    #pragma unroll
    for (int j = 0; j < 4; ++j) {
        float l = l_p[j];
        l += __shfl_xor(l, 1);
        l += __shfl_xor(l, 2);
        l += __shfl_xor(l, 4);
        l += __shfl_xor(l, 8);
        const float inv = 1.0f / l;
        const int t = qt * 128 + w * 16 + lg * 4 + j;
        __half* op = attn_pre + (((size_t)(s * TMQ + t)) * BB + b) * EE + h * HD + lc;
        #pragma unroll
        for (int nd = 0; nd < 4; ++nd)
            op[nd * 16] = __float2half(o[nd][j] * inv);
    }
}

// ---------------------------------------------------------------------------
// Launcher. Workspace: qh/kh/vth 12 MB each (fp16) | valsw 12 MB (fp32) |
// hs_h..Wr_h contiguous fp16 block (dst of cvt_all; hs_h aliased by apre_h)
// ---------------------------------------------------------------------------
extern "C" void kernel_launch(void* const* d_in, const int* in_sizes, int n_in,
                              void* d_out, int out_size, void* d_ws, size_t ws_size,
                              hipStream_t stream)
{
    const float* hs    = (const float*)d_in[0];
    const float* smask = (const float*)d_in[1];
    const float* nmask = (const float*)d_in[2];
    const int*   ibm   = (const int*)d_in[3];
    const int*   ibr   = (const int*)d_in[4];
    const float* Wq = (const float*)d_in[5];
    const float* bq = (const float*)d_in[6];
    const float* Wk = (const float*)d_in[7];
    const float* bk = (const float*)d_in[8];
    const float* Wv = (const float*)d_in[9];
    const float* bv = (const float*)d_in[10];
    const float* Wo = (const float*)d_in[11];
    const float* bo = (const float*)d_in[12];
    const float* Wr = (const float*)d_in[13];
    const float* br = (const float*)d_in[14];
    float* out = (float*)d_out;

    const size_t NQKV = (size_t)BHH * T3 * HD;   // 6,291,456
    __half* qh    = (__half*)d_ws;
    __half* kh    = qh + NQKV;
    __half* vth   = kh + NQKV;
    float*  valsw = (float*)(vth + NQKV);
    __half* hs_h  = (__half*)(valsw + (size_t)3 * BHH * TMQ * NBK);
    __half* apre_h = hs_h;                        // alias: hs_h dead before attn writes
    __half* Wq_h = hs_h + (size_t)T3 * BB * EE;   // contiguous with hs_h (cvt_all dst)
    __half* Wk_h = Wq_h + (size_t)EE * EE;
    __half* Wv_h = Wk_h + (size_t)EE * EE;
    __half* Wo_h = Wv_h + (size_t)EE * EE;
    __half* Wr_h = Wo_h + (size_t)EE * EE;

    dim3 blk(256);
    // all fp32 -> fp16 conversions in one launch (dst = hs_h..Wr_h contiguous)
    cvt_all<<<dim3(10752), blk, 0, stream>>>(hs, Wq, Wk, Wv, Wo, Wr, hs_h);

    // fused QKV + Wr projections (q,k -> (BH,T3,hd); v -> (BH,hd,T3); Wr -> vals)
    gemm16<0><<<dim3(14, 24), dim3(512), 0, stream>>>(hs_h, Wq_h, Wk_h, Wv_h, Wr_h,
                                                      bq, bk, bv, br,
                                                      qh, kh, vth, valsw);
    // MFMA fused attention (QBLK=128, 512 thr) -> fp16 apre (hs_h now dead)
    attn_mfma<<<dim3(768), dim3(512), 0, stream>>>(qh, kh, vth, valsw, smask, nmask,
                                                   ibm, ibr, apre_h);
    // output projection -> d_out (fp32)
    gemm16<2><<<dim3(4, 24), dim3(512), 0, stream>>>(apre_h, Wo_h, nullptr, nullptr, nullptr,
                                                     bo, nullptr, nullptr, nullptr,
                                                     out, nullptr, nullptr, nullptr);
}

// Round 15
// 207.843 us; speedup vs baseline: 1.1529x; 1.1529x over previous
//
#include <hip/hip_runtime.h>
#include <hip/hip_fp16.h>
#include <cstdint>

// Problem constants
#define T3   1536   // (NGRAM+1)*TM
#define TMQ  512    // TM
#define BB   4      // batch
#define EE   1024   // embed
#define HH   16     // heads
#define HD   64     // head dim
#define NBK  32     // buckets
#define BHH  64     // B*H

#define LOG2E 1.44269504f
#define SM_SHIFT 4.0f   // fixed softmax shift: p = exp(s - 4); safe since s <~ 12

typedef _Float16 half8 __attribute__((ext_vector_type(8)));
typedef float    f32x4 __attribute__((ext_vector_type(4)));

// XOR swizzle for [*][64] fp16 tiles (128B rows) - attn kernel (T2/G4).
#define SWZ(r, o) ((o) ^ (((r) & 7) << 4))

__device__ inline void gl_lds16(const void* g, void* l) {
    __builtin_amdgcn_global_load_lds(
        (const __attribute__((address_space(1))) uint32_t*)g,
        (__attribute__((address_space(3))) uint32_t*)l, 16, 0, 0);
}

#define VM_WAIT8() asm volatile("s_waitcnt vmcnt(8)" ::: "memory")
#define VM_WAIT4() asm volatile("s_waitcnt vmcnt(4)" ::: "memory")
#define VM_WAIT0() asm volatile("s_waitcnt vmcnt(0)" ::: "memory")
#define BARRIER()  __builtin_amdgcn_s_barrier()

// ---------------------------------------------------------------------------
// Fused fp32 -> fp16 conversion for all six tensors in ONE launch.
// dst layout contiguous: hs_h | Wq | Wk | Wv | Wo | Wr.
// ---------------------------------------------------------------------------
__global__ __launch_bounds__(256) void cvt_all(
    const float* __restrict__ hs, const float* __restrict__ Wq,
    const float* __restrict__ Wk, const float* __restrict__ Wv,
    const float* __restrict__ Wo, const float* __restrict__ Wr,
    __half* __restrict__ dst)
{
    const long i = (long)blockIdx.x * 256 + threadIdx.x;   // vec4 index
    const float* src; long off;
    if (i < 1572864L) { src = hs; off = i; }
    else {
        const long j = i - 1572864L;
        const int  w = (int)(j >> 18);
        const long r = j & 262143L;
        src = (w == 0) ? Wq : (w == 1) ? Wk : (w == 2) ? Wv : (w == 3) ? Wo : Wr;
        off = r;
    }
    const float4 v = ((const float4*)src)[off];
    const __half2 h0 = __floats2half2_rn(v.x, v.y);
    const __half2 h1 = __floats2half2_rn(v.z, v.w);
    uint2 u;
    u.x = *(const unsigned int*)&h0;
    u.y = *(const unsigned int*)&h1;
    ((uint2*)dst)[i] = u;
}

// ---------------------------------------------------------------------------
// fp16 MFMA GEMM (NT): C = (A @ W^T + bias) * scale + offs, K = 1024.
// r15: BM=BN=128 (r14's 256^2 regressed: VGPR cap 128 spilled acc, and
// 336-block grid at 1 blk/CU = 1.31 dispatch waves -> 66% tail util).
// BK=32 (64B rows), 256 thr (4 waves 2x2), 16x16x32 MFMA.
// DEPTH-2 PIPELINE WITH STATIC BUFFER NAMES: r11's depth-2 was null but
// rotated runtime pointers into ONE LDS symbol -> alias-analysis ordered
// the async gl_lds stores against every ds_read (the r9 placebo in a new
// costume). Here: THREE statically-named buffer pairs, modulo-3 unrolled
// schedule with literal names, vmcnt(8) steady state (2 tiles in flight
// across ~2 phases covers L2/HBM latency), tail vmcnt(4)/vmcnt(0).
// LDS 48 KB -> 3 blocks/CU (12 waves, best occupancy yet).
// Fragment/staging geometry = r10/r11 verbatim (passed, 0 conflicts):
// additive swizzle slot=(chunk+((row&7)>>1))&3 on source AND read.
// T1 XCD swizzle (r13). No min-waves hint (r5/r6: hints spill).
// MODE 0: fused QKV+Wr, grid (28,48). MODE 2: Wo, grid (8,48).
// ---------------------------------------------------------------------------
template<int MODE>
__global__ __launch_bounds__(256) void gemm16(
    const __half* __restrict__ A,
    const __half* __restrict__ Wa, const __half* __restrict__ Wb,
    const __half* __restrict__ Wc, const __half* __restrict__ Wd,
    const float* __restrict__ ba, const float* __restrict__ bb,
    const float* __restrict__ bc, const float* __restrict__ bd,
    void* __restrict__ oa, void* __restrict__ ob,
    void* __restrict__ oc, void* __restrict__ od)
{
    // six DISTINCT static LDS objects (alias analysis separates them)
    __shared__ __half As0[128 * 32], Bs0[128 * 32];   // 8 KB each
    __shared__ __half As1[128 * 32], Bs1[128 * 32];
    __shared__ __half As2[128 * 32], Bs2[128 * 32];   // total 48 KB

    const int tid  = threadIdx.x;
    const int w    = tid >> 6, lane = tid & 63;

    // T1 XCD swizzle (bijective: grid.y = 48 = 6*8)
    const int GX   = (MODE == 0) ? 28 : 8;
    const int bidl = blockIdx.x + GX * blockIdx.y;
    const int xcd  = bidl & 7, idx = bidl >> 3;
    const int bx   = idx % GX;
    const int by   = (idx / GX) * 8 + xcd;
    const int m0   = by * 128;

    const __half* Wsel; const float* bsel; void* osel;
    float scale, offs; int n0; int sel = 0;
    if (MODE == 0) {
        sel  = (bx < 24) ? (bx >> 3) : 3;
        n0   = (bx < 24) ? (bx & 7) * 128 : (bx - 24) * 128;
        Wsel = sel == 0 ? Wa : (sel == 1 ? Wb : (sel == 2 ? Wc : Wd));
        bsel = sel == 0 ? ba : (sel == 1 ? bb : (sel == 2 ? bc : bd));
        osel = sel == 0 ? oa : (sel == 1 ? ob : (sel == 2 ? oc : od));
        scale = (sel == 0) ? 0.125f * LOG2E : (sel == 3 ? LOG2E : 1.0f);
        offs  = (sel == 3) ? -SM_SHIFT * LOG2E : 0.0f;
    } else {
        n0 = bx * 128; Wsel = Wa; bsel = ba; osel = oa;
        scale = 1.0f; offs = 0.0f;
    }

    f32x4 acc[4][4];
    #pragma unroll
    for (int i = 0; i < 4; ++i)
        #pragma unroll
        for (int j = 0; j < 4; ++j) acc[i][j] = (f32x4){0.f, 0.f, 0.f, 0.f};

    const int wr = w >> 1, wc = w & 1;
    const int lrow = lane & 15, lkg = lane >> 4;
    // fragment base byte offsets: 64B rows; per-m advance = 16 rows = 1024 B
    const int aoff  = (wr * 64 + lrow) * 64;
    const int boff  = (wc * 64 + lrow) * 64;
    // read-side additive swizzle (r10 geometry, measured 0 conflicts)
    const int kbase = (((lkg + ((lrow & 7) >> 1)) & 3) << 4);

    // staging: wave w owns tile bytes [w*2048, w*2048+2048), 2 gl_lds of 1KB
    // per tensor; LDS slot s holds global chunk (s-d)&3, d=(row&7)>>1.
    const int stb0 = w * 2048, stb1 = w * 2048 + 1024;
    const int off0 = stb0 + lane * 16, off1 = stb1 + lane * 16;
    const int srow0 = off0 >> 6, srow1 = off1 >> 6;
    const int scol0 = (((((off0 >> 4) & 3) - ((srow0 & 7) >> 1)) & 3) << 4);
    const int scol1 = (((((off1 >> 4) & 3) - ((srow1 & 7) >> 1)) & 3) << 4);
    const char* Ab  = (const char*)A;
    const char* Wb8 = (const char*)Wsel;

#define STAGEK(AS, BS, K0) do {                                                   \
    gl_lds16(Ab  + (size_t)(m0 + srow0) * 2048 + (size_t)(K0) * 2 + scol0,        \
             (char*)(AS) + stb0);                                                 \
    gl_lds16(Wb8 + (size_t)(n0 + srow0) * 2048 + (size_t)(K0) * 2 + scol0,        \
             (char*)(BS) + stb0);                                                 \
    gl_lds16(Ab  + (size_t)(m0 + srow1) * 2048 + (size_t)(K0) * 2 + scol1,        \
             (char*)(AS) + stb1);                                                 \
    gl_lds16(Wb8 + (size_t)(n0 + srow1) * 2048 + (size_t)(K0) * 2 + scol1,        \
             (char*)(BS) + stb1);                                                 \
} while (0)

#define COMPUTEK(AS, BS) do {                                                     \
    half8 af[4], bf[4];                                                           \
    _Pragma("unroll")                                                             \
    for (int m = 0; m < 4; ++m)                                                   \
        af[m] = *(const half8*)((const char*)(AS) + aoff + m * 1024 + kbase);     \
    _Pragma("unroll")                                                             \
    for (int n = 0; n < 4; ++n)                                                   \
        bf[n] = *(const half8*)((const char*)(BS) + boff + n * 1024 + kbase);     \
    __builtin_amdgcn_s_setprio(1);                                                \
    _Pragma("unroll")                                                             \
    for (int m = 0; m < 4; ++m)                                                   \
        _Pragma("unroll")                                                         \
        for (int n = 0; n < 4; ++n)                                               \
            acc[m][n] = __builtin_amdgcn_mfma_f32_16x16x32_f16(af[m], bf[n],      \
                                                               acc[m][n], 0, 0, 0);\
    __builtin_amdgcn_s_setprio(0);                                                \
} while (0)

    // prologue: stage K-steps 0,1 (8 loads outstanding per wave)
    STAGEK(As0, Bs0, 0);
    STAGEK(As1, Bs1, 32);

    // 32 K-steps of BK=32; modulo-3 buffers with LITERAL names. Steady state:
    // stage(t+2) -> vmcnt(8) [t's 4 landed; t+1/t+2's 8 fly] -> barrier ->
    // compute(t) -> barrier. Buffer X re-staged >= 1 barrier after its reads.
    #pragma unroll 1
    for (int it = 0; it < 10; ++it) {
        const int kb0 = it * 96;
        STAGEK(As2, Bs2, kb0 + 64);  VM_WAIT8(); BARRIER();
        COMPUTEK(As0, Bs0);          BARRIER();
        STAGEK(As0, Bs0, kb0 + 96);  VM_WAIT8(); BARRIER();
        COMPUTEK(As1, Bs1);          BARRIER();
        STAGEK(As1, Bs1, kb0 + 128); VM_WAIT8(); BARRIER();
        COMPUTEK(As2, Bs2);          BARRIER();
    }
    // tail: steps 30 (As0, staged in it=9 ph1) and 31 (As1, staged in it=9 ph2)
    VM_WAIT4(); BARRIER();
    COMPUTEK(As0, Bs0);
    VM_WAIT0(); BARRIER();
    COMPUTEK(As1, Bs1);

#undef STAGEK
#undef COMPUTEK

    // epilogue: C/D layout col = lane&15, row = (lane>>4)*4 + reg
    const int col_l  = lane & 15;
    const int row_l4 = (lane >> 4) * 4;
    #pragma unroll
    for (int n = 0; n < 4; ++n) {
        const int gcol = n0 + wc * 64 + n * 16 + col_l;
        const float bias = bsel[gcol];
        #pragma unroll
        for (int m = 0; m < 4; ++m) {
            #pragma unroll
            for (int j = 0; j < 4; ++j) {
                const int grow = m0 + wr * 64 + m * 16 + row_l4 + j;
                const float cval = (acc[m][n][j] + bias) * scale + offs;
                if (MODE == 0) {
                    const int t3 = grow >> 2, bb2 = grow & 3;
                    if (sel == 3) {   // vals (stream, BH, TM, NB), fp32
                        const int st = t3 >> 9, tm = t3 & 511;
                        const int nb = gcol >> 4, hh2 = gcol & 15;
                        ((float*)osel)[(((size_t)(st * BHH + bb2 * HH + hh2)) * TMQ + tm) * NBK + nb] = cval;
                    } else {
                        const int hh2 = gcol >> 6, d = gcol & 63;
                        __half* oh = (__half*)osel;
                        const __half hv = __float2half(cval);
                        if (sel == 2)  // V transposed: (BH, hd, T3)
                            oh[((size_t)((bb2 * HH + hh2) * HD + d)) * T3 + t3] = hv;
                        else           // Q, K: (BH, T3, hd)
                            oh[(((size_t)(bb2 * HH + hh2)) * T3 + t3) * HD + d] = hv;
                    }
                } else {
                    ((float*)osel)[(size_t)grow * EE + gcol] = cval;
                }
            }
        }
    }
}

// ---------------------------------------------------------------------------
// MFMA fused attention, QBLK=128 (r13 verbatim): block = (s, bh, 128 q-rows),
// 8 waves x 16 q-rows. Fixed-shift softmax, per-lane l reduced once.
// Register-prefetch of K/Vt + idx/mask (T14), setprio (T5). LDS 48 KB.
// Balanced XCD map: 768 blocks, per XCD 64 ngram + 32 main, ngram first.
// NOTE (r5/r6): NEVER add a min-waves hint (spills the prefetch state).
// ---------------------------------------------------------------------------
__global__ __launch_bounds__(512) void attn_mfma(
    const __half* __restrict__ q, const __half* __restrict__ k,
    const __half* __restrict__ vt, const float* __restrict__ vals,
    const float* __restrict__ self_mask, const float* __restrict__ ngram_mask,
    const int* __restrict__ ibm, const int* __restrict__ ibr,
    __half* __restrict__ attn_pre)
{
    __shared__ __half QP [128 * 64];   // 16 KB: Q staging -> reused as P
    __shared__ __half Ks [64 * 64];    //  8 KB [key][d] swizzled
    __shared__ __half Vts[64 * 64];    //  8 KB [d][key] swizzled
    __shared__ float  vals_s[128 * NBK];   // 16 KB

    // balanced XCD mapping: xcd = bid&7; rr<64 -> ngram, rr>=64 -> main
    const int bid = blockIdx.x;
    const int xcd = bid & 7, rr = bid >> 3;          // rr in [0,96)
    int s, bh, qt;
    if (rr < 64) { const int g = xcd * 64 + rr; s = 1 + (g >> 8); bh = (g >> 2) & 63; qt = g & 3; }
    else         { const int mi = xcd * 32 + (rr - 64); s = 0; bh = mi >> 2; qt = mi & 3; }
    const int b = bh >> 4, h = bh & 15;
    const int tid = threadIdx.x;                     // 0..511
    const int w = tid >> 6, lane = tid & 63;         // w 0..7
    const int lc = lane & 15, lg = lane >> 4;
    const int nch = (s == 0) ? 8 : 16;

    // ---- stage Q (swizzled, into QP) + vals (linear): 16 KB each ----
    {
        const char* qg = (const char*)(q + ((size_t)bh * T3 + s * TMQ + qt * 128) * HD);
        const char* vg = (const char*)(vals + (((size_t)s * BHH + bh) * TMQ + qt * 128) * NBK);
        #pragma unroll
        for (int p = 0; p < 2; ++p) {
            const int u = tid + p * 512;             // 0..1023
            const int row = u >> 3, sub = (u & 7) * 16;
            *(uint4*)((char*)QP + row * 128 + SWZ(row, sub)) = *(const uint4*)(qg + (size_t)u * 16);
            *(uint4*)((char*)vals_s + (size_t)u * 16)        = *(const uint4*)(vg + (size_t)u * 16);
        }
    }

    // ---- prologue prefetch: chunk 0 K/Vt + idx/mask into registers ----
    uint4 ku0, vu0;
    int   ix[4][4];
    float mk[4][4];
    {
        const char* kg = (const char*)(k + (size_t)bh * T3 * HD);          // t3b(0)=0
        const char* vg = (const char*)(vt + (size_t)bh * HD * T3);
        ku0 = *(const uint4*)(kg + (size_t)tid * 16);
        vu0 = *(const uint4*)(vg + (size_t)(tid >> 3) * (T3 * 2) + (tid & 7) * 16);
        #pragma unroll
        for (int j = 0; j < 4; ++j) {
            const int t = qt * 128 + w * 16 + lg * 4 + j;
            const int* ip; const float* mp;
            if (s == 0) { ip = ibm + ((size_t)b * TMQ + t) * TMQ + lc;
                          mp = self_mask + (size_t)t * TMQ + lc; }
            else        { ip = ibr + ((size_t)b * TMQ + t) * (2 * TMQ) + lc;
                          mp = ngram_mask + ((size_t)(s - 1) * TMQ + t) * (2 * TMQ) + lc; }
            #pragma unroll
            for (int n = 0; n < 4; ++n) { ix[j][n] = ip[n * 16]; mk[j][n] = mp[n * 16]; }
        }
    }
    __syncthreads();   // QP(Q)/vals_s staged

    // hoisted Q A-fragments (row = local q = w*16 + lc, in [0,128))
    half8 aq[2];
    {
        const int qr = w * 16 + lc;
        const char* qb = (const char*)QP + qr * 128;
        aq[0] = *(const half8*)(qb + SWZ(qr, lg * 16));
        aq[1] = *(const half8*)(qb + SWZ(qr, 64 + lg * 16));
    }

    f32x4 o[4];
    #pragma unroll
    for (int nd = 0; nd < 4; ++nd) o[nd] = (f32x4){0.f, 0.f, 0.f, 0.f};
    float l_p[4] = {0.f, 0.f, 0.f, 0.f};

    for (int c = 0; c < nch; ++c) {
        // ---- ds_write prefetched K/Vt (one uint4 per tensor per thread) ----
        if (c > 0) __syncthreads();   // all waves done reading Ks/Vts of c-1
        {
            const int r0 = tid >> 3, s0 = (tid & 7) * 16;   // r0 0..63
            *(uint4*)((char*)Ks  + r0 * 128 + SWZ(r0, s0)) = ku0;
            *(uint4*)((char*)Vts + r0 * 128 + SWZ(r0, s0)) = vu0;
        }
        __syncthreads();              // staged (also fences aq reads, c==0)

        // ---- issue next chunk's K/Vt loads (hide under QK+exp+PV) ----
        if (c + 1 < nch) {
            const int jn  = (c + 1) * 64;
            const int t3n = (jn < TMQ) ? jn : s * TMQ + (jn - TMQ);
            const char* kg = (const char*)(k + ((size_t)bh * T3 + t3n) * HD);
            const char* vg = (const char*)(vt + (size_t)bh * HD * T3 + t3n);
            ku0 = *(const uint4*)(kg + (size_t)tid * 16);
            vu0 = *(const uint4*)(vg + (size_t)(tid >> 3) * (T3 * 2) + (tid & 7) * 16);
        }

        // ---- QK^T: D[q_local][key] (q pre-scaled by 0.125*log2e) ----
        f32x4 sc[4];
        #pragma unroll
        for (int n = 0; n < 4; ++n) sc[n] = (f32x4){0.f, 0.f, 0.f, 0.f};
        __builtin_amdgcn_s_setprio(1);
        #pragma unroll
        for (int ks = 0; ks < 2; ++ks) {
            #pragma unroll
            for (int n = 0; n < 4; ++n) {
                const int kr = n * 16 + lc;
                const half8 bk = *(const half8*)((const char*)Ks + kr * 128 + SWZ(kr, ks * 64 + lg * 16));
                sc[n] = __builtin_amdgcn_mfma_f32_16x16x32_f16(aq[ks], bk, sc[n], 0, 0, 0);
            }
        }
        __builtin_amdgcn_s_setprio(0);

        // ---- gather + exp2 + P write + per-lane partial sum ----
        // element: row q_local = w*16 + lg*4 + j, col key = n*16 + lc
        #pragma unroll
        for (int j = 0; j < 4; ++j) {
            const int ql = w * 16 + lg * 4 + j;
            const float* vr = vals_s + ql * NBK;
            float p[4];
            #pragma unroll
            for (int n = 0; n < 4; ++n) {
                const float sv = fmaf(mk[j][n], LOG2E, sc[n][j] + vr[ix[j][n]]);
                p[n] = __builtin_amdgcn_exp2f(sv);
            }
            l_p[j] += (p[0] + p[1]) + (p[2] + p[3]);
            char* pb = (char*)QP + ql * 128;
            *(__half*)(pb + SWZ(ql, (0 * 16 + lc) * 2)) = __float2half(p[0]);
            *(__half*)(pb + SWZ(ql, (1 * 16 + lc) * 2)) = __float2half(p[1]);
            *(__half*)(pb + SWZ(ql, (2 * 16 + lc) * 2)) = __float2half(p[2]);
            *(__half*)(pb + SWZ(ql, (3 * 16 + lc) * 2)) = __float2half(p[3]);
        }

        // ---- issue next chunk's idx/mask loads ----
        if (c + 1 < nch) {
            const int jn = (c + 1) * 64;
            #pragma unroll
            for (int j = 0; j < 4; ++j) {
                const int t = qt * 128 + w * 16 + lg * 4 + j;
                const int* ip; const float* mp;
                if (s == 0) { ip = ibm + ((size_t)b * TMQ + t) * TMQ + jn + lc;
                              mp = self_mask + (size_t)t * TMQ + jn + lc; }
                else        { ip = ibr + ((size_t)b * TMQ + t) * (2 * TMQ) + jn + lc;
                              mp = ngram_mask + ((size_t)(s - 1) * TMQ + t) * (2 * TMQ) + jn + lc; }
                #pragma unroll
                for (int n = 0; n < 4; ++n) { ix[j][n] = ip[n * 16]; mk[j][n] = mp[n * 16]; }
            }
        }
        __threadfence_block();   // P-writes visible (QP rows are per-wave)

        // ---- PV: O[q_local][d] += P[q][key] * Vt[d][key] ----
        __builtin_amdgcn_s_setprio(1);
        #pragma unroll
        for (int ks = 0; ks < 2; ++ks) {
            const int ar = w * 16 + lc;
            const half8 ap = *(const half8*)((const char*)QP + ar * 128 + SWZ(ar, ks * 64 + lg * 16));
            #pragma unroll
            for (int nd = 0; nd < 4; ++nd) {
                const int vr2 = nd * 16 + lc;
                const half8 bv = *(const half8*)((const char*)Vts + vr2 * 128 + SWZ(vr2, ks * 64 + lg * 16));
                o[nd] = __builtin_amdgcn_mfma_f32_16x16x32_f16(ap, bv, o[nd], 0, 0, 0);
            }
        }
        __builtin_amdgcn_s_setprio(0);
    }

    // ---- final cross-lane sum reduce (once) + normalize + write fp16 ----
    #pragma unroll
    for (int j = 0; j < 4; ++j) {
        float l = l_p[j];
        l += __shfl_xor(l, 1);
        l += __shfl_xor(l, 2);
        l += __shfl_xor(l, 4);
        l += __shfl_xor(l, 8);
        const float inv = 1.0f / l;
        const int t = qt * 128 + w * 16 + lg * 4 + j;
        __half* op = attn_pre + (((size_t)(s * TMQ + t)) * BB + b) * EE + h * HD + lc;
        #pragma unroll
        for (int nd = 0; nd < 4; ++nd)
            op[nd * 16] = __float2half(o[nd][j] * inv);
    }
}

// ---------------------------------------------------------------------------
// Launcher. Workspace: qh/kh/vth 12 MB each (fp16) | valsw 12 MB (fp32) |
// hs_h..Wr_h contiguous fp16 block (dst of cvt_all; hs_h aliased by apre_h)
// ---------------------------------------------------------------------------
extern "C" void kernel_launch(void* const* d_in, const int* in_sizes, int n_in,
                              void* d_out, int out_size, void* d_ws, size_t ws_size,
                              hipStream_t stream)
{
    const float* hs    = (const float*)d_in[0];
    const float* smask = (const float*)d_in[1];
    const float* nmask = (const float*)d_in[2];
    const int*   ibm   = (const int*)d_in[3];
    const int*   ibr   = (const int*)d_in[4];
    const float* Wq = (const float*)d_in[5];
    const float* bq = (const float*)d_in[6];
    const float* Wk = (const float*)d_in[7];
    const float* bk = (const float*)d_in[8];
    const float* Wv = (const float*)d_in[9];
    const float* bv = (const float*)d_in[10];
    const float* Wo = (const float*)d_in[11];
    const float* bo = (const float*)d_in[12];
    const float* Wr = (const float*)d_in[13];
    const float* br = (const float*)d_in[14];
    float* out = (float*)d_out;

    const size_t NQKV = (size_t)BHH * T3 * HD;   // 6,291,456
    __half* qh    = (__half*)d_ws;
    __half* kh    = qh + NQKV;
    __half* vth   = kh + NQKV;
    float*  valsw = (float*)(vth + NQKV);
    __half* hs_h  = (__half*)(valsw + (size_t)3 * BHH * TMQ * NBK);
    __half* apre_h = hs_h;                        // alias: hs_h dead before attn writes
    __half* Wq_h = hs_h + (size_t)T3 * BB * EE;   // contiguous with hs_h (cvt_all dst)
    __half* Wk_h = Wq_h + (size_t)EE * EE;
    __half* Wv_h = Wk_h + (size_t)EE * EE;
    __half* Wo_h = Wv_h + (size_t)EE * EE;
    __half* Wr_h = Wo_h + (size_t)EE * EE;

    dim3 blk(256);
    // all fp32 -> fp16 conversions in one launch (dst = hs_h..Wr_h contiguous)
    cvt_all<<<dim3(10752), blk, 0, stream>>>(hs, Wq, Wk, Wv, Wo, Wr, hs_h);

    // fused QKV + Wr projections (q,k -> (BH,T3,hd); v -> (BH,hd,T3); Wr -> vals)
    gemm16<0><<<dim3(28, 48), blk, 0, stream>>>(hs_h, Wq_h, Wk_h, Wv_h, Wr_h,
                                                bq, bk, bv, br,
                                                qh, kh, vth, valsw);
    // MFMA fused attention (QBLK=128, 512 thr) -> fp16 apre (hs_h now dead)
    attn_mfma<<<dim3(768), dim3(512), 0, stream>>>(qh, kh, vth, valsw, smask, nmask,
                                                   ibm, ibr, apre_h);
    // output projection -> d_out (fp32)
    gemm16<2><<<dim3(8, 48), blk, 0, stream>>>(apre_h, Wo_h, nullptr, nullptr, nullptr,
                                               bo, nullptr, nullptr, nullptr,
                                               out, nullptr, nullptr, nullptr);
}

// Round 16
// 203.099 us; speedup vs baseline: 1.1799x; 1.0234x over previous
//
#include <hip/hip_runtime.h>
#include <hip/hip_fp16.h>
#include <cstdint>

// Problem constants
#define T3   1536   // (NGRAM+1)*TM
#define TMQ  512    // TM
#define BB   4      // batch
#define EE   1024   // embed
#define HH   16     // heads
#define HD   64     // head dim
#define NBK  32     // buckets
#define BHH  64     // B*H

#define LOG2E 1.44269504f
#define SM_SHIFT 4.0f   // fixed softmax shift: p = exp(s - 4); safe since s <~ 12

typedef _Float16 half8 __attribute__((ext_vector_type(8)));
typedef float    f32x4 __attribute__((ext_vector_type(4)));

// XOR swizzle for [*][64] fp16 tiles (128B rows) - attn kernel + gemm BK=64 (T2/G4).
#define SWZ(r, o) ((o) ^ (((r) & 7) << 4))

__device__ inline void gl_lds16(const void* g, void* l) {
    __builtin_amdgcn_global_load_lds(
        (const __attribute__((address_space(1))) uint32_t*)g,
        (__attribute__((address_space(3))) uint32_t*)l, 16, 0, 0);
}

#define VM_WAIT0() asm volatile("s_waitcnt vmcnt(0)" ::: "memory")
#define BARRIER()  __builtin_amdgcn_s_barrier()

// ---------------------------------------------------------------------------
// Fused fp32 -> fp16 conversion for all six tensors in ONE launch.
// dst layout contiguous: hs_h | Wq | Wk | Wv | Wo | Wr.
// ---------------------------------------------------------------------------
__global__ __launch_bounds__(256) void cvt_all(
    const float* __restrict__ hs, const float* __restrict__ Wq,
    const float* __restrict__ Wk, const float* __restrict__ Wv,
    const float* __restrict__ Wo, const float* __restrict__ Wr,
    __half* __restrict__ dst)
{
    const long i = (long)blockIdx.x * 256 + threadIdx.x;   // vec4 index
    const float* src; long off;
    if (i < 1572864L) { src = hs; off = i; }
    else {
        const long j = i - 1572864L;
        const int  w = (int)(j >> 18);
        const long r = j & 262143L;
        src = (w == 0) ? Wq : (w == 1) ? Wk : (w == 2) ? Wv : (w == 3) ? Wo : Wr;
        off = r;
    }
    const float4 v = ((const float4*)src)[off];
    const __half2 h0 = __floats2half2_rn(v.x, v.y);
    const __half2 h1 = __floats2half2_rn(v.z, v.w);
    uint2 u;
    u.x = *(const unsigned int*)&h0;
    u.y = *(const unsigned int*)&h1;
    ((uint2*)dst)[i] = u;
}

// ---------------------------------------------------------------------------
// fp16 MFMA GEMM (NT) - r13 VERBATIM (best measured: MODE0 ~95us).
// BM=BN=128, BK=64 (128B rows), 256 thr (4 waves 2x2), 16x16x32 MFMA.
// 2-phase: static buffer pairs, ONE vmcnt(0)+s_barrier per K-step AFTER
// compute; r8 conflict-free swizzle; T1 XCD swizzle; setprio on MFMA.
// 9 schedule variants (r8-r12,r15: single/double/depth-2/counted-vmcnt)
// all land 95-111us at MfmaUtil 17-19% -> structure plateau; accepted.
// LDS 64 KB -> 2 blocks/CU. No min-waves hint (r5/r6: hints spill).
// MODE 0: fused QKV+Wr, grid (28,48). MODE 2: Wo, grid (8,48).
// ---------------------------------------------------------------------------
template<int MODE>
__global__ __launch_bounds__(256) void gemm16(
    const __half* __restrict__ A,
    const __half* __restrict__ Wa, const __half* __restrict__ Wb,
    const __half* __restrict__ Wc, const __half* __restrict__ Wd,
    const float* __restrict__ ba, const float* __restrict__ bb,
    const float* __restrict__ bc, const float* __restrict__ bd,
    void* __restrict__ oa, void* __restrict__ ob,
    void* __restrict__ oc, void* __restrict__ od)
{
    __shared__ __half As0[128 * 64];   // 16 KB each
    __shared__ __half Bs0[128 * 64];
    __shared__ __half As1[128 * 64];
    __shared__ __half Bs1[128 * 64];   // total 64 KB -> 2 blocks/CU

    const int tid  = threadIdx.x;
    const int w    = tid >> 6, lane = tid & 63;

    // T1 XCD swizzle (bijective: grid.y = 48 = 6*8)
    const int GX   = (MODE == 0) ? 28 : 8;
    const int bidl = blockIdx.x + GX * blockIdx.y;
    const int xcd  = bidl & 7, idx = bidl >> 3;
    const int bx   = idx % GX;
    const int by   = (idx / GX) * 8 + xcd;
    const int m0   = by * 128;

    const __half* Wsel; const float* bsel; void* osel;
    float scale, offs; int n0; int sel = 0;
    if (MODE == 0) {
        sel  = (bx < 24) ? (bx >> 3) : 3;
        n0   = (bx < 24) ? (bx & 7) * 128 : (bx - 24) * 128;
        Wsel = sel == 0 ? Wa : (sel == 1 ? Wb : (sel == 2 ? Wc : Wd));
        bsel = sel == 0 ? ba : (sel == 1 ? bb : (sel == 2 ? bc : bd));
        osel = sel == 0 ? oa : (sel == 1 ? ob : (sel == 2 ? oc : od));
        scale = (sel == 0) ? 0.125f * LOG2E : (sel == 3 ? LOG2E : 1.0f);
        offs  = (sel == 3) ? -SM_SHIFT * LOG2E : 0.0f;
    } else {
        n0 = bx * 128; Wsel = Wa; bsel = ba; osel = oa;
        scale = 1.0f; offs = 0.0f;
    }

    f32x4 acc[4][4];
    #pragma unroll
    for (int i = 0; i < 4; ++i)
        #pragma unroll
        for (int j = 0; j < 4; ++j) acc[i][j] = (f32x4){0.f, 0.f, 0.f, 0.f};

    const int wr = w >> 1, wc = w & 1;
    const int lrow = lane & 15, lkg = lane >> 4;
    const int aoff = (wr * 64 + lrow) * 128;
    const int boff = (wc * 64 + lrow) * 128;
    const int rswz = (lrow & 7) << 4;      // read-side XOR (row&7 == lrow&7)

    const int tilebase = w * 4096;
    const char* Ab  = (const char*)A;
    const char* Wb8 = (const char*)Wsel;
    int srow[4], scol[4];
    #pragma unroll
    for (int i = 0; i < 4; ++i) {
        const int off = tilebase + i * 1024 + lane * 16;
        srow[i] = off >> 7;                                 // tile row 0..127
        scol[i] = (((off >> 4) & 7) ^ (srow[i] & 7)) * 16;  // swizzled src col
    }

#define STAGEK(AS, BS, K0) do {                                                   \
    _Pragma("unroll")                                                             \
    for (int i = 0; i < 4; ++i) {                                                 \
        gl_lds16(Ab  + (size_t)(m0 + srow[i]) * 2048 + (size_t)(K0) * 2 + scol[i],\
                 (char*)(AS) + tilebase + i * 1024);                              \
        gl_lds16(Wb8 + (size_t)(n0 + srow[i]) * 2048 + (size_t)(K0) * 2 + scol[i],\
                 (char*)(BS) + tilebase + i * 1024);                              \
    }                                                                             \
} while (0)

#define COMPUTEK(AS, BS) do {                                                     \
    _Pragma("unroll")                                                             \
    for (int ks = 0; ks < 2; ++ks) {                                              \
        const int kb = (ks * 64 + lkg * 16) ^ rswz;                               \
        half8 af[4], bf[4];                                                       \
        _Pragma("unroll")                                                         \
        for (int m = 0; m < 4; ++m)                                               \
            af[m] = *(const half8*)((const char*)(AS) + aoff + m * 2048 + kb);    \
        _Pragma("unroll")                                                         \
        for (int n = 0; n < 4; ++n)                                               \
            bf[n] = *(const half8*)((const char*)(BS) + boff + n * 2048 + kb);    \
        __builtin_amdgcn_s_setprio(1);                                            \
        _Pragma("unroll")                                                         \
        for (int m = 0; m < 4; ++m)                                               \
            _Pragma("unroll")                                                     \
            for (int n = 0; n < 4; ++n)                                           \
                acc[m][n] = __builtin_amdgcn_mfma_f32_16x16x32_f16(af[m], bf[n],  \
                                                                   acc[m][n], 0, 0, 0);\
        __builtin_amdgcn_s_setprio(0);                                            \
    }                                                                             \
} while (0)

    STAGEK(As0, Bs0, 0);
    VM_WAIT0();
    BARRIER();

    #pragma unroll 1
    for (int t = 0; t < 8; ++t) {
        const int kA = t * 128;
        STAGEK(As1, Bs1, kA + 64);
        COMPUTEK(As0, Bs0);
        VM_WAIT0();
        BARRIER();
        if (t < 7) STAGEK(As0, Bs0, kA + 128);
        COMPUTEK(As1, Bs1);
        VM_WAIT0();
        BARRIER();
    }

#undef STAGEK
#undef COMPUTEK

    const int col_l  = lane & 15;
    const int row_l4 = (lane >> 4) * 4;
    #pragma unroll
    for (int n = 0; n < 4; ++n) {
        const int gcol = n0 + wc * 64 + n * 16 + col_l;
        const float bias = bsel[gcol];
        #pragma unroll
        for (int m = 0; m < 4; ++m) {
            #pragma unroll
            for (int j = 0; j < 4; ++j) {
                const int grow = m0 + wr * 64 + m * 16 + row_l4 + j;
                const float cval = (acc[m][n][j] + bias) * scale + offs;
                if (MODE == 0) {
                    const int t3 = grow >> 2, bb2 = grow & 3;
                    if (sel == 3) {   // vals (stream, BH, TM, NB), fp32
                        const int st = t3 >> 9, tm = t3 & 511;
                        const int nb = gcol >> 4, hh2 = gcol & 15;
                        ((float*)osel)[(((size_t)(st * BHH + bb2 * HH + hh2)) * TMQ + tm) * NBK + nb] = cval;
                    } else {
                        const int hh2 = gcol >> 6, d = gcol & 63;
                        __half* oh = (__half*)osel;
                        const __half hv = __float2half(cval);
                        if (sel == 2)  // V transposed: (BH, hd, T3)
                            oh[((size_t)((bb2 * HH + hh2) * HD + d)) * T3 + t3] = hv;
                        else           // Q, K: (BH, T3, hd)
                            oh[(((size_t)(bb2 * HH + hh2)) * T3 + t3) * HD + d] = hv;
                    }
                } else {
                    ((float*)osel)[(size_t)grow * EE + gcol] = cval;
                }
            }
        }
    }
}

// ---------------------------------------------------------------------------
// MFMA fused attention, QBLK=128, r16: SWAPPED QK^T (T12 enabling trick).
// sc = mfma(K_frag, Q_frag) -> D[key][q]: each lane holds P for ONE q-row
// (q = w*16+lc) at j-contiguous keys (n*16+lg*4+j). Benefits (attn was
// measured DS-throughput-bound, ~430cy DS vs 155cy MFMA per wave-chunk):
//   - P-writes: 16x ds_write_b16 -> 4x ds_write_b64 (pack via half2)
//   - idx/mask prefetch: 32 scalar -> 8 vector loads (int4/float4)
//   - softmax still shfl-free in hot loop (per-lane partial l; 2 shfl_xor
//     + 4 shfl at the END only)
// Q/K LDS reads, PV (A-frag read at row w*16+lc), staging, output mapping
// unchanged from the passing r13 kernel. Fixed-shift softmax (exp2-folded).
// LDS 48 KB. Balanced XCD map: 768 blocks, 64 ngram + 32 main per XCD.
// NOTE (r5/r6): NEVER add a min-waves hint (spills the prefetch state).
// ---------------------------------------------------------------------------
__global__ __launch_bounds__(512) void attn_mfma(
    const __half* __restrict__ q, const __half* __restrict__ k,
    const __half* __restrict__ vt, const float* __restrict__ vals,
    const float* __restrict__ self_mask, const float* __restrict__ ngram_mask,
    const int* __restrict__ ibm, const int* __restrict__ ibr,
    __half* __restrict__ attn_pre)
{
    __shared__ __half QP [128 * 64];   // 16 KB: Q staging -> reused as P
    __shared__ __half Ks [64 * 64];    //  8 KB [key][d] swizzled
    __shared__ __half Vts[64 * 64];    //  8 KB [d][key] swizzled
    __shared__ float  vals_s[128 * NBK];   // 16 KB

    // balanced XCD mapping: xcd = bid&7; rr<64 -> ngram, rr>=64 -> main
    const int bid = blockIdx.x;
    const int xcd = bid & 7, rr = bid >> 3;          // rr in [0,96)
    int s, bh, qt;
    if (rr < 64) { const int g = xcd * 64 + rr; s = 1 + (g >> 8); bh = (g >> 2) & 63; qt = g & 3; }
    else         { const int mi = xcd * 32 + (rr - 64); s = 0; bh = mi >> 2; qt = mi & 3; }
    const int b = bh >> 4, h = bh & 15;
    const int tid = threadIdx.x;                     // 0..511
    const int w = tid >> 6, lane = tid & 63;         // w 0..7
    const int lc = lane & 15, lg = lane >> 4;
    const int nch = (s == 0) ? 8 : 16;
    const int tq  = qt * 128 + w * 16 + lc;          // this lane's q row (global t)

    // ---- stage Q (swizzled, into QP) + vals (linear): 16 KB each ----
    {
        const char* qg = (const char*)(q + ((size_t)bh * T3 + s * TMQ + qt * 128) * HD);
        const char* vg = (const char*)(vals + (((size_t)s * BHH + bh) * TMQ + qt * 128) * NBK);
        #pragma unroll
        for (int p = 0; p < 2; ++p) {
            const int u = tid + p * 512;             // 0..1023
            const int row = u >> 3, sub = (u & 7) * 16;
            *(uint4*)((char*)QP + row * 128 + SWZ(row, sub)) = *(const uint4*)(qg + (size_t)u * 16);
            *(uint4*)((char*)vals_s + (size_t)u * 16)        = *(const uint4*)(vg + (size_t)u * 16);
        }
    }

    // ---- prologue prefetch: chunk 0 K/Vt + idx/mask (VECTORIZED) ----
    uint4  ku0, vu0;
    int4   ix4[4];
    float4 mk4[4];
    {
        const char* kg = (const char*)(k + (size_t)bh * T3 * HD);          // t3b(0)=0
        const char* vg = (const char*)(vt + (size_t)bh * HD * T3);
        ku0 = *(const uint4*)(kg + (size_t)tid * 16);
        vu0 = *(const uint4*)(vg + (size_t)(tid >> 3) * (T3 * 2) + (tid & 7) * 16);
        #pragma unroll
        for (int n = 0; n < 4; ++n) {
            const int jj = n * 16 + lg * 4;
            if (s == 0) {
                ix4[n] = *(const int4*)  (ibm + ((size_t)b * TMQ + tq) * TMQ + jj);
                mk4[n] = *(const float4*)(self_mask + (size_t)tq * TMQ + jj);
            } else {
                ix4[n] = *(const int4*)  (ibr + ((size_t)b * TMQ + tq) * (2 * TMQ) + jj);
                mk4[n] = *(const float4*)(ngram_mask + ((size_t)(s - 1) * TMQ + tq) * (2 * TMQ) + jj);
            }
        }
    }
    __syncthreads();   // QP(Q)/vals_s staged

    // hoisted Q fragments (row = q local = w*16 + lc) — B-operand after swap
    half8 aq[2];
    {
        const int qr = w * 16 + lc;
        const char* qb = (const char*)QP + qr * 128;
        aq[0] = *(const half8*)(qb + SWZ(qr, lg * 16));
        aq[1] = *(const half8*)(qb + SWZ(qr, 64 + lg * 16));
    }

    f32x4 o[4];
    #pragma unroll
    for (int nd = 0; nd < 4; ++nd) o[nd] = (f32x4){0.f, 0.f, 0.f, 0.f};
    float l_p = 0.f;

    for (int c = 0; c < nch; ++c) {
        // ---- ds_write prefetched K/Vt (one uint4 per tensor per thread) ----
        if (c > 0) __syncthreads();   // all waves done reading Ks/Vts of c-1
        {
            const int r0 = tid >> 3, s0 = (tid & 7) * 16;   // r0 0..63
            *(uint4*)((char*)Ks  + r0 * 128 + SWZ(r0, s0)) = ku0;
            *(uint4*)((char*)Vts + r0 * 128 + SWZ(r0, s0)) = vu0;
        }
        __syncthreads();              // staged (also fences aq reads, c==0)

        // ---- issue next chunk's K/Vt loads (hide under QK+exp+PV) ----
        if (c + 1 < nch) {
            const int jn  = (c + 1) * 64;
            const int t3n = (jn < TMQ) ? jn : s * TMQ + (jn - TMQ);
            const char* kg = (const char*)(k + ((size_t)bh * T3 + t3n) * HD);
            const char* vg = (const char*)(vt + (size_t)bh * HD * T3 + t3n);
            ku0 = *(const uint4*)(kg + (size_t)tid * 16);
            vu0 = *(const uint4*)(vg + (size_t)(tid >> 3) * (T3 * 2) + (tid & 7) * 16);
        }

        // ---- QK^T SWAPPED: sc[n] = mfma(K, Q) -> D[key][q=lc] ----
        f32x4 sc[4];
        #pragma unroll
        for (int n = 0; n < 4; ++n) sc[n] = (f32x4){0.f, 0.f, 0.f, 0.f};
        __builtin_amdgcn_s_setprio(1);
        #pragma unroll
        for (int ks = 0; ks < 2; ++ks) {
            #pragma unroll
            for (int n = 0; n < 4; ++n) {
                const int kr = n * 16 + lc;
                const half8 bk = *(const half8*)((const char*)Ks + kr * 128 + SWZ(kr, ks * 64 + lg * 16));
                sc[n] = __builtin_amdgcn_mfma_f32_16x16x32_f16(bk, aq[ks], sc[n], 0, 0, 0);
            }
        }
        __builtin_amdgcn_s_setprio(0);

        // ---- gather + exp2 + pack + b64 P write + per-lane partial sum ----
        // lane element: q = w*16+lc (fixed), key = n*16 + lg*4 + j
        {
            const float* vr = vals_s + (w * 16 + lc) * NBK;
            char* pb = (char*)QP + (w * 16 + lc) * 128;
            const int prow = w * 16 + lc;
            #pragma unroll
            for (int n = 0; n < 4; ++n) {
                const float p0 = __builtin_amdgcn_exp2f(fmaf(mk4[n].x, LOG2E, sc[n][0] + vr[ix4[n].x]));
                const float p1 = __builtin_amdgcn_exp2f(fmaf(mk4[n].y, LOG2E, sc[n][1] + vr[ix4[n].y]));
                const float p2 = __builtin_amdgcn_exp2f(fmaf(mk4[n].z, LOG2E, sc[n][2] + vr[ix4[n].z]));
                const float p3 = __builtin_amdgcn_exp2f(fmaf(mk4[n].w, LOG2E, sc[n][3] + vr[ix4[n].w]));
                l_p += (p0 + p1) + (p2 + p3);
                const __half2 h01 = __floats2half2_rn(p0, p1);
                const __half2 h23 = __floats2half2_rn(p2, p3);
                uint2 u;
                u.x = *(const unsigned int*)&h01;
                u.y = *(const unsigned int*)&h23;
                *(uint2*)(pb + SWZ(prow, n * 32 + lg * 8)) = u;
            }
        }

        // ---- issue next chunk's idx/mask loads (vectorized) ----
        if (c + 1 < nch) {
            const int jb = (c + 1) * 64;
            #pragma unroll
            for (int n = 0; n < 4; ++n) {
                const int jj = jb + n * 16 + lg * 4;
                if (s == 0) {
                    ix4[n] = *(const int4*)  (ibm + ((size_t)b * TMQ + tq) * TMQ + jj);
                    mk4[n] = *(const float4*)(self_mask + (size_t)tq * TMQ + jj);
                } else {
                    ix4[n] = *(const int4*)  (ibr + ((size_t)b * TMQ + tq) * (2 * TMQ) + jj);
                    mk4[n] = *(const float4*)(ngram_mask + ((size_t)(s - 1) * TMQ + tq) * (2 * TMQ) + jj);
                }
            }
        }
        __threadfence_block();   // P-writes visible (QP rows are per-wave)

        // ---- PV: O[q][d] += P[q][key] * Vt[d][key] (unchanged) ----
        __builtin_amdgcn_s_setprio(1);
        #pragma unroll
        for (int ks = 0; ks < 2; ++ks) {
            const int ar = w * 16 + lc;
            const half8 ap = *(const half8*)((const char*)QP + ar * 128 + SWZ(ar, ks * 64 + lg * 16));
            #pragma unroll
            for (int nd = 0; nd < 4; ++nd) {
                const int vr2 = nd * 16 + lc;
                const half8 bv = *(const half8*)((const char*)Vts + vr2 * 128 + SWZ(vr2, ks * 64 + lg * 16));
                o[nd] = __builtin_amdgcn_mfma_f32_16x16x32_f16(ap, bv, o[nd], 0, 0, 0);
            }
        }
        __builtin_amdgcn_s_setprio(0);
    }

    // ---- final: reduce l across lg (lanes lc+16g), redistribute, write ----
    float l = l_p;
    l += __shfl_xor(l, 16);
    l += __shfl_xor(l, 32);          // lanes with same lc now hold l[q=w*16+lc]
    #pragma unroll
    for (int j = 0; j < 4; ++j) {
        const float lj  = __shfl(l, lg * 4 + j);   // lane with lc == lg*4+j
        const float inv = 1.0f / lj;
        const int t = qt * 128 + w * 16 + lg * 4 + j;
        __half* op = attn_pre + (((size_t)(s * TMQ + t)) * BB + b) * EE + h * HD + lc;
        #pragma unroll
        for (int nd = 0; nd < 4; ++nd)
            op[nd * 16] = __float2half(o[nd][j] * inv);
    }
}

// ---------------------------------------------------------------------------
// Launcher. Workspace: qh/kh/vth 12 MB each (fp16) | valsw 12 MB (fp32) |
// hs_h..Wr_h contiguous fp16 block (dst of cvt_all; hs_h aliased by apre_h)
// ---------------------------------------------------------------------------
extern "C" void kernel_launch(void* const* d_in, const int* in_sizes, int n_in,
                              void* d_out, int out_size, void* d_ws, size_t ws_size,
                              hipStream_t stream)
{
    const float* hs    = (const float*)d_in[0];
    const float* smask = (const float*)d_in[1];
    const float* nmask = (const float*)d_in[2];
    const int*   ibm   = (const int*)d_in[3];
    const int*   ibr   = (const int*)d_in[4];
    const float* Wq = (const float*)d_in[5];
    const float* bq = (const float*)d_in[6];
    const float* Wk = (const float*)d_in[7];
    const float* bk = (const float*)d_in[8];
    const float* Wv = (const float*)d_in[9];
    const float* bv = (const float*)d_in[10];
    const float* Wo = (const float*)d_in[11];
    const float* bo = (const float*)d_in[12];
    const float* Wr = (const float*)d_in[13];
    const float* br = (const float*)d_in[14];
    float* out = (float*)d_out;

    const size_t NQKV = (size_t)BHH * T3 * HD;   // 6,291,456
    __half* qh    = (__half*)d_ws;
    __half* kh    = qh + NQKV;
    __half* vth   = kh + NQKV;
    float*  valsw = (float*)(vth + NQKV);
    __half* hs_h  = (__half*)(valsw + (size_t)3 * BHH * TMQ * NBK);
    __half* apre_h = hs_h;                        // alias: hs_h dead before attn writes
    __half* Wq_h = hs_h + (size_t)T3 * BB * EE;   // contiguous with hs_h (cvt_all dst)
    __half* Wk_h = Wq_h + (size_t)EE * EE;
    __half* Wv_h = Wk_h + (size_t)EE * EE;
    __half* Wo_h = Wv_h + (size_t)EE * EE;
    __half* Wr_h = Wo_h + (size_t)EE * EE;

    dim3 blk(256);
    // all fp32 -> fp16 conversions in one launch (dst = hs_h..Wr_h contiguous)
    cvt_all<<<dim3(10752), blk, 0, stream>>>(hs, Wq, Wk, Wv, Wo, Wr, hs_h);

    // fused QKV + Wr projections (q,k -> (BH,T3,hd); v -> (BH,hd,T3); Wr -> vals)
    gemm16<0><<<dim3(28, 48), blk, 0, stream>>>(hs_h, Wq_h, Wk_h, Wv_h, Wr_h,
                                                bq, bk, bv, br,
                                                qh, kh, vth, valsw);
    // MFMA fused attention (QBLK=128, 512 thr) -> fp16 apre (hs_h now dead)
    attn_mfma<<<dim3(768), dim3(512), 0, stream>>>(qh, kh, vth, valsw, smask, nmask,
                                                   ibm, ibr, apre_h);
    // output projection -> d_out (fp32)
    gemm16<2><<<dim3(8, 48), blk, 0, stream>>>(apre_h, Wo_h, nullptr, nullptr, nullptr,
                                               bo, nullptr, nullptr, nullptr,
                                               out, nullptr, nullptr, nullptr);
}

// Round 17
// 196.834 us; speedup vs baseline: 1.2174x; 1.0318x over previous
//
#include <hip/hip_runtime.h>
#include <hip/hip_fp16.h>
#include <cstdint>

// Problem constants
#define T3   1536   // (NGRAM+1)*TM
#define TMQ  512    // TM
#define BB   4      // batch
#define EE   1024   // embed
#define HH   16     // heads
#define HD   64     // head dim
#define NBK  32     // buckets
#define BHH  64     // B*H

#define LOG2E 1.44269504f
#define SM_SHIFT 4.0f   // fixed softmax shift: p = exp(s - 4); safe since s <~ 12

typedef _Float16 half8 __attribute__((ext_vector_type(8)));
typedef float    f32x4 __attribute__((ext_vector_type(4)));

// XOR swizzle for [*][64] fp16 tiles (128B rows) - attn kernel + gemm BK=64 (T2/G4).
#define SWZ(r, o) ((o) ^ (((r) & 7) << 4))

__device__ inline void gl_lds16(const void* g, void* l) {
    __builtin_amdgcn_global_load_lds(
        (const __attribute__((address_space(1))) uint32_t*)g,
        (__attribute__((address_space(3))) uint32_t*)l, 16, 0, 0);
}

#define VM_WAIT0() asm volatile("s_waitcnt vmcnt(0)" ::: "memory")
#define BARRIER()  __builtin_amdgcn_s_barrier()

// ---------------------------------------------------------------------------
// Fused fp32 -> fp16 conversion for all six tensors in ONE launch.
// dst layout contiguous: hs_h | Wq | Wk | Wv | Wo | Wr.
// ---------------------------------------------------------------------------
__global__ __launch_bounds__(256) void cvt_all(
    const float* __restrict__ hs, const float* __restrict__ Wq,
    const float* __restrict__ Wk, const float* __restrict__ Wv,
    const float* __restrict__ Wo, const float* __restrict__ Wr,
    __half* __restrict__ dst)
{
    const long i = (long)blockIdx.x * 256 + threadIdx.x;   // vec4 index
    const float* src; long off;
    if (i < 1572864L) { src = hs; off = i; }
    else {
        const long j = i - 1572864L;
        const int  w = (int)(j >> 18);
        const long r = j & 262143L;
        src = (w == 0) ? Wq : (w == 1) ? Wk : (w == 2) ? Wv : (w == 3) ? Wo : Wr;
        off = r;
    }
    const float4 v = ((const float4*)src)[off];
    const __half2 h0 = __floats2half2_rn(v.x, v.y);
    const __half2 h1 = __floats2half2_rn(v.z, v.w);
    uint2 u;
    u.x = *(const unsigned int*)&h0;
    u.y = *(const unsigned int*)&h1;
    ((uint2*)dst)[i] = u;
}

// ---------------------------------------------------------------------------
// fp16 MFMA GEMM (NT) - r13 configuration (best measured: MODE0 ~95us).
// BM=BN=128, BK=64 (128B rows), 256 thr (4 waves 2x2), 16x16x32 MFMA.
// 2-phase: static buffer pairs, ONE vmcnt(0)+s_barrier per K-step AFTER
// compute; r8 conflict-free swizzle; T1 XCD swizzle; setprio on MFMA.
// Plateau evidence: 9 schedule variants (r8-r15) all 95-111us at MfmaUtil
// 17-19%; guide m102 shape-curve shows the verified m97-structure gets
// 90-320 TF at N=1024-2048, so our 475 TF at K=1024 is above that curve ->
// shape-limited ceiling for this structure. Accepted.
// LDS 64 KB -> 2 blocks/CU. No min-waves hint (r5/r6: hints spill).
// MODE 0: fused QKV+Wr, grid (28,48). MODE 2: Wo, grid (8,48).
// ---------------------------------------------------------------------------
template<int MODE>
__global__ __launch_bounds__(256) void gemm16(
    const __half* __restrict__ A,
    const __half* __restrict__ Wa, const __half* __restrict__ Wb,
    const __half* __restrict__ Wc, const __half* __restrict__ Wd,
    const float* __restrict__ ba, const float* __restrict__ bb,
    const float* __restrict__ bc, const float* __restrict__ bd,
    void* __restrict__ oa, void* __restrict__ ob,
    void* __restrict__ oc, void* __restrict__ od)
{
    __shared__ __half As0[128 * 64];   // 16 KB each
    __shared__ __half Bs0[128 * 64];
    __shared__ __half As1[128 * 64];
    __shared__ __half Bs1[128 * 64];   // total 64 KB -> 2 blocks/CU

    const int tid  = threadIdx.x;
    const int w    = tid >> 6, lane = tid & 63;

    // T1 XCD swizzle (bijective: grid.y = 48 = 6*8)
    const int GX   = (MODE == 0) ? 28 : 8;
    const int bidl = blockIdx.x + GX * blockIdx.y;
    const int xcd  = bidl & 7, idx = bidl >> 3;
    const int bx   = idx % GX;
    const int by   = (idx / GX) * 8 + xcd;
    const int m0   = by * 128;

    const __half* Wsel; const float* bsel; void* osel;
    float scale, offs; int n0; int sel = 0;
    if (MODE == 0) {
        sel  = (bx < 24) ? (bx >> 3) : 3;
        n0   = (bx < 24) ? (bx & 7) * 128 : (bx - 24) * 128;
        Wsel = sel == 0 ? Wa : (sel == 1 ? Wb : (sel == 2 ? Wc : Wd));
        bsel = sel == 0 ? ba : (sel == 1 ? bb : (sel == 2 ? bc : bd));
        osel = sel == 0 ? oa : (sel == 1 ? ob : (sel == 2 ? oc : od));
        scale = (sel == 0) ? 0.125f * LOG2E : (sel == 3 ? LOG2E : 1.0f);
        offs  = (sel == 3) ? -SM_SHIFT * LOG2E : 0.0f;
    } else {
        n0 = bx * 128; Wsel = Wa; bsel = ba; osel = oa;
        scale = 1.0f; offs = 0.0f;
    }

    f32x4 acc[4][4];
    #pragma unroll
    for (int i = 0; i < 4; ++i)
        #pragma unroll
        for (int j = 0; j < 4; ++j) acc[i][j] = (f32x4){0.f, 0.f, 0.f, 0.f};

    const int wr = w >> 1, wc = w & 1;
    const int lrow = lane & 15, lkg = lane >> 4;
    const int aoff = (wr * 64 + lrow) * 128;
    const int boff = (wc * 64 + lrow) * 128;
    const int rswz = (lrow & 7) << 4;      // read-side XOR (row&7 == lrow&7)

    const int tilebase = w * 4096;
    const char* Ab  = (const char*)A;
    const char* Wb8 = (const char*)Wsel;
    int srow[4], scol[4];
    #pragma unroll
    for (int i = 0; i < 4; ++i) {
        const int off = tilebase + i * 1024 + lane * 16;
        srow[i] = off >> 7;                                 // tile row 0..127
        scol[i] = (((off >> 4) & 7) ^ (srow[i] & 7)) * 16;  // swizzled src col
    }

#define STAGEK(AS, BS, K0) do {                                                   \
    _Pragma("unroll")                                                             \
    for (int i = 0; i < 4; ++i) {                                                 \
        gl_lds16(Ab  + (size_t)(m0 + srow[i]) * 2048 + (size_t)(K0) * 2 + scol[i],\
                 (char*)(AS) + tilebase + i * 1024);                              \
        gl_lds16(Wb8 + (size_t)(n0 + srow[i]) * 2048 + (size_t)(K0) * 2 + scol[i],\
                 (char*)(BS) + tilebase + i * 1024);                              \
    }                                                                             \
} while (0)

#define COMPUTEK(AS, BS) do {                                                     \
    _Pragma("unroll")                                                             \
    for (int ks = 0; ks < 2; ++ks) {                                              \
        const int kb = (ks * 64 + lkg * 16) ^ rswz;                               \
        half8 af[4], bf[4];                                                       \
        _Pragma("unroll")                                                         \
        for (int m = 0; m < 4; ++m)                                               \
            af[m] = *(const half8*)((const char*)(AS) + aoff + m * 2048 + kb);    \
        _Pragma("unroll")                                                         \
        for (int n = 0; n < 4; ++n)                                               \
            bf[n] = *(const half8*)((const char*)(BS) + boff + n * 2048 + kb);    \
        __builtin_amdgcn_s_setprio(1);                                            \
        _Pragma("unroll")                                                         \
        for (int m = 0; m < 4; ++m)                                               \
            _Pragma("unroll")                                                     \
            for (int n = 0; n < 4; ++n)                                           \
                acc[m][n] = __builtin_amdgcn_mfma_f32_16x16x32_f16(af[m], bf[n],  \
                                                                   acc[m][n], 0, 0, 0);\
        __builtin_amdgcn_s_setprio(0);                                            \
    }                                                                             \
} while (0)

    STAGEK(As0, Bs0, 0);
    VM_WAIT0();
    BARRIER();

    #pragma unroll 1
    for (int t = 0; t < 8; ++t) {
        const int kA = t * 128;
        STAGEK(As1, Bs1, kA + 64);
        COMPUTEK(As0, Bs0);
        VM_WAIT0();
        BARRIER();
        if (t < 7) STAGEK(As0, Bs0, kA + 128);
        COMPUTEK(As1, Bs1);
        VM_WAIT0();
        BARRIER();
    }

#undef STAGEK
#undef COMPUTEK

    const int col_l  = lane & 15;
    const int row_l4 = (lane >> 4) * 4;
    #pragma unroll
    for (int n = 0; n < 4; ++n) {
        const int gcol = n0 + wc * 64 + n * 16 + col_l;
        const float bias = bsel[gcol];
        #pragma unroll
        for (int m = 0; m < 4; ++m) {
            #pragma unroll
            for (int j = 0; j < 4; ++j) {
                const int grow = m0 + wr * 64 + m * 16 + row_l4 + j;
                const float cval = (acc[m][n][j] + bias) * scale + offs;
                if (MODE == 0) {
                    const int t3 = grow >> 2, bb2 = grow & 3;
                    if (sel == 3) {   // vals (stream, BH, TM, NB), fp32
                        const int st = t3 >> 9, tm = t3 & 511;
                        const int nb = gcol >> 4, hh2 = gcol & 15;
                        ((float*)osel)[(((size_t)(st * BHH + bb2 * HH + hh2)) * TMQ + tm) * NBK + nb] = cval;
                    } else {
                        const int hh2 = gcol >> 6, d = gcol & 63;
                        __half* oh = (__half*)osel;
                        const __half hv = __float2half(cval);
                        if (sel == 2)  // V transposed: (BH, hd, T3)
                            oh[((size_t)((bb2 * HH + hh2) * HD + d)) * T3 + t3] = hv;
                        else           // Q, K: (BH, T3, hd)
                            oh[(((size_t)(bb2 * HH + hh2)) * T3 + t3) * HD + d] = hv;
                    }
                } else {
                    ((float*)osel)[(size_t)grow * EE + gcol] = cval;
                }
            }
        }
    }
}

// ---------------------------------------------------------------------------
// MFMA fused attention, QBLK=128 - r13 configuration RESTORED (r16's swapped
// QK^T regressed attn ~60 -> 95us: the per-lane-row int4/float4 idx/mask
// loads were 64-distinct-cache-line transactions per instruction (8x the
// coalesced scalar form), and LDS conflicts tripled to 7.7M. Reverted.)
// Block = (s, bh, 128 q-rows), 8 waves x 16 q-rows. Fixed-shift softmax
// (p = exp2(qk' + vals'[idx] + mask*log2e)), per-lane l, reduced once.
// Register-prefetch of K/Vt + idx/mask (T14), setprio (T5). LDS 48 KB.
// Balanced XCD map: 768 blocks, per XCD 64 ngram + 32 main, ngram first.
// NOTE (r5/r6): NEVER add a min-waves hint (spills the prefetch state).
// ---------------------------------------------------------------------------
__global__ __launch_bounds__(512) void attn_mfma(
    const __half* __restrict__ q, const __half* __restrict__ k,
    const __half* __restrict__ vt, const float* __restrict__ vals,
    const float* __restrict__ self_mask, const float* __restrict__ ngram_mask,
    const int* __restrict__ ibm, const int* __restrict__ ibr,
    __half* __restrict__ attn_pre)
{
    __shared__ __half QP [128 * 64];   // 16 KB: Q staging -> reused as P
    __shared__ __half Ks [64 * 64];    //  8 KB [key][d] swizzled
    __shared__ __half Vts[64 * 64];    //  8 KB [d][key] swizzled
    __shared__ float  vals_s[128 * NBK];   // 16 KB

    // balanced XCD mapping: xcd = bid&7; rr<64 -> ngram, rr>=64 -> main
    const int bid = blockIdx.x;
    const int xcd = bid & 7, rr = bid >> 3;          // rr in [0,96)
    int s, bh, qt;
    if (rr < 64) { const int g = xcd * 64 + rr; s = 1 + (g >> 8); bh = (g >> 2) & 63; qt = g & 3; }
    else         { const int mi = xcd * 32 + (rr - 64); s = 0; bh = mi >> 2; qt = mi & 3; }
    const int b = bh >> 4, h = bh & 15;
    const int tid = threadIdx.x;                     // 0..511
    const int w = tid >> 6, lane = tid & 63;         // w 0..7
    const int lc = lane & 15, lg = lane >> 4;
    const int nch = (s == 0) ? 8 : 16;

    // ---- stage Q (swizzled, into QP) + vals (linear): 16 KB each ----
    {
        const char* qg = (const char*)(q + ((size_t)bh * T3 + s * TMQ + qt * 128) * HD);
        const char* vg = (const char*)(vals + (((size_t)s * BHH + bh) * TMQ + qt * 128) * NBK);
        #pragma unroll
        for (int p = 0; p < 2; ++p) {
            const int u = tid + p * 512;             // 0..1023
            const int row = u >> 3, sub = (u & 7) * 16;
            *(uint4*)((char*)QP + row * 128 + SWZ(row, sub)) = *(const uint4*)(qg + (size_t)u * 16);
            *(uint4*)((char*)vals_s + (size_t)u * 16)        = *(const uint4*)(vg + (size_t)u * 16);
        }
    }

    // ---- prologue prefetch: chunk 0 K/Vt + idx/mask into registers ----
    uint4 ku0, vu0;
    int   ix[4][4];
    float mk[4][4];
    {
        const char* kg = (const char*)(k + (size_t)bh * T3 * HD);          // t3b(0)=0
        const char* vg = (const char*)(vt + (size_t)bh * HD * T3);
        ku0 = *(const uint4*)(kg + (size_t)tid * 16);
        vu0 = *(const uint4*)(vg + (size_t)(tid >> 3) * (T3 * 2) + (tid & 7) * 16);
        #pragma unroll
        for (int j = 0; j < 4; ++j) {
            const int t = qt * 128 + w * 16 + lg * 4 + j;
            const int* ip; const float* mp;
            if (s == 0) { ip = ibm + ((size_t)b * TMQ + t) * TMQ + lc;
                          mp = self_mask + (size_t)t * TMQ + lc; }
            else        { ip = ibr + ((size_t)b * TMQ + t) * (2 * TMQ) + lc;
                          mp = ngram_mask + ((size_t)(s - 1) * TMQ + t) * (2 * TMQ) + lc; }
            #pragma unroll
            for (int n = 0; n < 4; ++n) { ix[j][n] = ip[n * 16]; mk[j][n] = mp[n * 16]; }
        }
    }
    __syncthreads();   // QP(Q)/vals_s staged

    // hoisted Q A-fragments (row = local q = w*16 + lc, in [0,128))
    half8 aq[2];
    {
        const int qr = w * 16 + lc;
        const char* qb = (const char*)QP + qr * 128;
        aq[0] = *(const half8*)(qb + SWZ(qr, lg * 16));
        aq[1] = *(const half8*)(qb + SWZ(qr, 64 + lg * 16));
    }

    f32x4 o[4];
    #pragma unroll
    for (int nd = 0; nd < 4; ++nd) o[nd] = (f32x4){0.f, 0.f, 0.f, 0.f};
    float l_p[4] = {0.f, 0.f, 0.f, 0.f};

    for (int c = 0; c < nch; ++c) {
        // ---- ds_write prefetched K/Vt (one uint4 per tensor per thread) ----
        if (c > 0) __syncthreads();   // all waves done reading Ks/Vts of c-1
        {
            const int r0 = tid >> 3, s0 = (tid & 7) * 16;   // r0 0..63
            *(uint4*)((char*)Ks  + r0 * 128 + SWZ(r0, s0)) = ku0;
            *(uint4*)((char*)Vts + r0 * 128 + SWZ(r0, s0)) = vu0;
        }
        __syncthreads();              // staged (also fences aq reads, c==0)

        // ---- issue next chunk's K/Vt loads (hide under QK+exp+PV) ----
        if (c + 1 < nch) {
            const int jn  = (c + 1) * 64;
            const int t3n = (jn < TMQ) ? jn : s * TMQ + (jn - TMQ);
            const char* kg = (const char*)(k + ((size_t)bh * T3 + t3n) * HD);
            const char* vg = (const char*)(vt + (size_t)bh * HD * T3 + t3n);
            ku0 = *(const uint4*)(kg + (size_t)tid * 16);
            vu0 = *(const uint4*)(vg + (size_t)(tid >> 3) * (T3 * 2) + (tid & 7) * 16);
        }

        // ---- QK^T: D[q_local][key] (q pre-scaled by 0.125*log2e) ----
        f32x4 sc[4];
        #pragma unroll
        for (int n = 0; n < 4; ++n) sc[n] = (f32x4){0.f, 0.f, 0.f, 0.f};
        __builtin_amdgcn_s_setprio(1);
        #pragma unroll
        for (int ks = 0; ks < 2; ++ks) {
            #pragma unroll
            for (int n = 0; n < 4; ++n) {
                const int kr = n * 16 + lc;
                const half8 bk = *(const half8*)((const char*)Ks + kr * 128 + SWZ(kr, ks * 64 + lg * 16));
                sc[n] = __builtin_amdgcn_mfma_f32_16x16x32_f16(aq[ks], bk, sc[n], 0, 0, 0);
            }
        }
        __builtin_amdgcn_s_setprio(0);

        // ---- gather + exp2 + P write + per-lane partial sum ----
        // element: row q_local = w*16 + lg*4 + j, col key = n*16 + lc
        #pragma unroll
        for (int j = 0; j < 4; ++j) {
            const int ql = w * 16 + lg * 4 + j;
            const float* vr = vals_s + ql * NBK;
            float p[4];
            #pragma unroll
            for (int n = 0; n < 4; ++n) {
                const float sv = fmaf(mk[j][n], LOG2E, sc[n][j] + vr[ix[j][n]]);
                p[n] = __builtin_amdgcn_exp2f(sv);
            }
            l_p[j] += (p[0] + p[1]) + (p[2] + p[3]);
            char* pb = (char*)QP + ql * 128;
            *(__half*)(pb + SWZ(ql, (0 * 16 + lc) * 2)) = __float2half(p[0]);
            *(__half*)(pb + SWZ(ql, (1 * 16 + lc) * 2)) = __float2half(p[1]);
            *(__half*)(pb + SWZ(ql, (2 * 16 + lc) * 2)) = __float2half(p[2]);
            *(__half*)(pb + SWZ(ql, (3 * 16 + lc) * 2)) = __float2half(p[3]);
        }

        // ---- issue next chunk's idx/mask loads ----
        if (c + 1 < nch) {
            const int jn = (c + 1) * 64;
            #pragma unroll
            for (int j = 0; j < 4; ++j) {
                const int t = qt * 128 + w * 16 + lg * 4 + j;
                const int* ip; const float* mp;
                if (s == 0) { ip = ibm + ((size_t)b * TMQ + t) * TMQ + jn + lc;
                              mp = self_mask + (size_t)t * TMQ + jn + lc; }
                else        { ip = ibr + ((size_t)b * TMQ + t) * (2 * TMQ) + jn + lc;
                              mp = ngram_mask + ((size_t)(s - 1) * TMQ + t) * (2 * TMQ) + jn + lc; }
                #pragma unroll
                for (int n = 0; n < 4; ++n) { ix[j][n] = ip[n * 16]; mk[j][n] = mp[n * 16]; }
            }
        }
        __threadfence_block();   // P-writes visible (QP rows are per-wave)

        // ---- PV: O[q_local][d] += P[q][key] * Vt[d][key] ----
        __builtin_amdgcn_s_setprio(1);
        #pragma unroll
        for (int ks = 0; ks < 2; ++ks) {
            const int ar = w * 16 + lc;
            const half8 ap = *(const half8*)((const char*)QP + ar * 128 + SWZ(ar, ks * 64 + lg * 16));
            #pragma unroll
            for (int nd = 0; nd < 4; ++nd) {
                const int vr2 = nd * 16 + lc;
                const half8 bv = *(const half8*)((const char*)Vts + vr2 * 128 + SWZ(vr2, ks * 64 + lg * 16));
                o[nd] = __builtin_amdgcn_mfma_f32_16x16x32_f16(ap, bv, o[nd], 0, 0, 0);
            }
        }
        __builtin_amdgcn_s_setprio(0);
    }

    // ---- final cross-lane sum reduce (once) + normalize + write fp16 ----
    #pragma unroll
    for (int j = 0; j < 4; ++j) {
        float l = l_p[j];
        l += __shfl_xor(l, 1);
        l += __shfl_xor(l, 2);
        l += __shfl_xor(l, 4);
        l += __shfl_xor(l, 8);
        const float inv = 1.0f / l;
        const int t = qt * 128 + w * 16 + lg * 4 + j;
        __half* op = attn_pre + (((size_t)(s * TMQ + t)) * BB + b) * EE + h * HD + lc;
        #pragma unroll
        for (int nd = 0; nd < 4; ++nd)
            op[nd * 16] = __float2half(o[nd][j] * inv);
    }
}

// ---------------------------------------------------------------------------
// Launcher. Workspace: qh/kh/vth 12 MB each (fp16) | valsw 12 MB (fp32) |
// hs_h..Wr_h contiguous fp16 block (dst of cvt_all; hs_h aliased by apre_h)
// ---------------------------------------------------------------------------
extern "C" void kernel_launch(void* const* d_in, const int* in_sizes, int n_in,
                              void* d_out, int out_size, void* d_ws, size_t ws_size,
                              hipStream_t stream)
{
    const float* hs    = (const float*)d_in[0];
    const float* smask = (const float*)d_in[1];
    const float* nmask = (const float*)d_in[2];
    const int*   ibm   = (const int*)d_in[3];
    const int*   ibr   = (const int*)d_in[4];
    const float* Wq = (const float*)d_in[5];
    const float* bq = (const float*)d_in[6];
    const float* Wk = (const float*)d_in[7];
    const float* bk = (const float*)d_in[8];
    const float* Wv = (const float*)d_in[9];
    const float* bv = (const float*)d_in[10];
    const float* Wo = (const float*)d_in[11];
    const float* bo = (const float*)d_in[12];
    const float* Wr = (const float*)d_in[13];
    const float* br = (const float*)d_in[14];
    float* out = (float*)d_out;

    const size_t NQKV = (size_t)BHH * T3 * HD;   // 6,291,456
    __half* qh    = (__half*)d_ws;
    __half* kh    = qh + NQKV;
    __half* vth   = kh + NQKV;
    float*  valsw = (float*)(vth + NQKV);
    __half* hs_h  = (__half*)(valsw + (size_t)3 * BHH * TMQ * NBK);
    __half* apre_h = hs_h;                        // alias: hs_h dead before attn writes
    __half* Wq_h = hs_h + (size_t)T3 * BB * EE;   // contiguous with hs_h (cvt_all dst)
    __half* Wk_h = Wq_h + (size_t)EE * EE;
    __half* Wv_h = Wk_h + (size_t)EE * EE;
    __half* Wo_h = Wv_h + (size_t)EE * EE;
    __half* Wr_h = Wo_h + (size_t)EE * EE;

    dim3 blk(256);
    // all fp32 -> fp16 conversions in one launch (dst = hs_h..Wr_h contiguous)
    cvt_all<<<dim3(10752), blk, 0, stream>>>(hs, Wq, Wk, Wv, Wo, Wr, hs_h);

    // fused QKV + Wr projections (q,k -> (BH,T3,hd); v -> (BH,hd,T3); Wr -> vals)
    gemm16<0><<<dim3(28, 48), blk, 0, stream>>>(hs_h, Wq_h, Wk_h, Wv_h, Wr_h,
                                                bq, bk, bv, br,
                                                qh, kh, vth, valsw);
    // MFMA fused attention (QBLK=128, 512 thr) -> fp16 apre (hs_h now dead)
    attn_mfma<<<dim3(768), dim3(512), 0, stream>>>(qh, kh, vth, valsw, smask, nmask,
                                                   ibm, ibr, apre_h);
    // output projection -> d_out (fp32)
    gemm16<2><<<dim3(8, 48), blk, 0, stream>>>(apre_h, Wo_h, nullptr, nullptr, nullptr,
                                               bo, nullptr, nullptr, nullptr,
                                               out, nullptr, nullptr, nullptr);
}